// Round 1
// baseline (307.127 us; speedup 1.0000x reference)
//
#include <hip/hip_runtime.h>
#include <hip/hip_bf16.h>
#include <cstdint>

namespace {

constexpr int NPIX = 12544;   // 4*56*56
constexpr int BTOK = 3136;    // 4*28*28 pooled tokens

__device__ __forceinline__ float wsum(float v) {
#pragma unroll
  for (int m = 32; m; m >>= 1) v += __shfl_xor(v, m, 64);
  return v;
}

__device__ __forceinline__ uint32_t packbf(float a, float b) {
  uint32_t ua = __builtin_bit_cast(uint32_t, a);
  ua = ua + 0x7fffu + ((ua >> 16) & 1u);
  uint32_t ub = __builtin_bit_cast(uint32_t, b);
  ub = ub + 0x7fffu + ((ub >> 16) & 1u);
  return (ua >> 16) | (ub & 0xffff0000u);
}
__device__ __forceinline__ float bflo(uint32_t u) { return __builtin_bit_cast(float, u << 16); }
__device__ __forceinline__ float bfhi(uint32_t u) { return __builtin_bit_cast(float, u & 0xffff0000u); }

__device__ __forceinline__ float gelu_exact(float v) {
  return 0.5f * v * (1.0f + erff(v * 0.70710678118654752f));
}

// ---------------- Kernel 1: NAT LN1 + QKV GEMM (per branch) ----------------
// grid = 3 branches * 392 groups of 32 pixels
__global__ __launch_bounds__(256) void k_nat_ln_qkv(
    const float* __restrict__ x, const float* __restrict__ ln_g,
    const float* __restrict__ ln_b, const float* __restrict__ qkv_w,
    const float* __restrict__ qkv_b, float* __restrict__ qkv_out) {
  __shared__ float sW[64 * 192];
  __shared__ float sB[192];
  __shared__ float sXn[32][65];
  int br = blockIdx.x / 392;
  int grp = blockIdx.x % 392;
  int tid = threadIdx.x;
  const float* W = qkv_w + br * 64 * 192;
  for (int i = tid * 4; i < 64 * 192; i += 1024)
    *(float4*)&sW[i] = *(const float4*)&W[i];
  if (tid < 192) sB[tid] = qkv_b[br * 192 + tid];
  int lane = tid & 63, wid = tid >> 6;
  float g = ln_g[br * 64 + lane], bb = ln_b[br * 64 + lane];
#pragma unroll
  for (int i = 0; i < 8; ++i) {
    int pl = wid * 8 + i;
    int pg = grp * 32 + pl;
    float v = x[(size_t)pg * 256 + br * 64 + lane];
    float s1 = wsum(v), s2 = wsum(v * v);
    float m = s1 * (1.f / 64.f);
    float var = s2 * (1.f / 64.f) - m * m;
    sXn[pl][lane] = (v - m) * rsqrtf(var + 1e-5f) * g + bb;
  }
  __syncthreads();
  int pl = tid >> 3, o0 = (tid & 7) * 24;
  float acc[24];
#pragma unroll
  for (int j = 0; j < 24; ++j) acc[j] = sB[o0 + j];
  for (int c = 0; c < 64; ++c) {
    float a = sXn[pl][c];
    const float4* wr = (const float4*)&sW[c * 192 + o0];
#pragma unroll
    for (int j4 = 0; j4 < 6; ++j4) {
      float4 w = wr[j4];
      acc[4 * j4 + 0] = fmaf(a, w.x, acc[4 * j4 + 0]);
      acc[4 * j4 + 1] = fmaf(a, w.y, acc[4 * j4 + 1]);
      acc[4 * j4 + 2] = fmaf(a, w.z, acc[4 * j4 + 2]);
      acc[4 * j4 + 3] = fmaf(a, w.w, acc[4 * j4 + 3]);
    }
  }
  int pg = grp * 32 + pl;
  float* op = qkv_out + ((size_t)br * NPIX + pg) * 192 + o0;
#pragma unroll
  for (int j = 0; j < 24; ++j) {
    float v = acc[j];
    if (o0 + j < 64) v *= 0.25f;  // q scale: d^-0.5 = 16^-0.5 = 0.25
    op[j] = v;
  }
}

// ---------------- Kernel 2: NAT neighborhood attention ----------------
// one thread per (branch, pixel, head). grid = 3*12544*4/256 = 588 blocks
__global__ __launch_bounds__(256) void k_nat_attn(
    const float* __restrict__ qkv, const float* __restrict__ rpb,
    float* __restrict__ att) {
  int gid = blockIdx.x * 256 + threadIdx.x;
  int br = gid / (NPIX * 4);
  int t = gid % (NPIX * 4);
  int pix = t >> 2, h = t & 3;
  int b = pix / 3136;
  int y = (pix / 56) % 56, xx = pix % 56;
  int sy = min(max(y - 3, 0), 49), sx = min(max(xx - 3, 0), 49);
  const float* qp = qkv + ((size_t)br * NPIX + pix) * 192 + h * 16;
  float q[16];
#pragma unroll
  for (int i = 0; i < 16; i += 4) *(float4*)&q[i] = *(const float4*)&qp[i];
  // rpb base at (ry0, rx0): logit(a,c) bias = rp[a*13 + c]
  const float* rp = rpb + (br * 4 + h) * 169 + (sy - y + 6) * 13 + (sx - xx + 6);
  float m = -1e30f, l = 0.f;
  float acc[16];
#pragma unroll
  for (int i = 0; i < 16; ++i) acc[i] = 0.f;
  for (int a = 0; a < 7; ++a) {
    const float* kbase =
        qkv + ((size_t)br * NPIX + (b * 3136 + (sy + a) * 56 + sx)) * 192 + 64 + h * 16;
    for (int c = 0; c < 7; ++c) {
      const float* kp = kbase + c * 192;
      float kk[16];
#pragma unroll
      for (int i = 0; i < 16; i += 4) *(float4*)&kk[i] = *(const float4*)&kp[i];
      float s = 0.f;
#pragma unroll
      for (int i = 0; i < 16; ++i) s = fmaf(q[i], kk[i], s);
      s += rp[a * 13 + c];
      float mn = fmaxf(m, s);
      float sc = __expf(m - mn);
      float p = __expf(s - mn);
      l = l * sc + p;
      float vv[16];
#pragma unroll
      for (int i = 0; i < 16; i += 4) *(float4*)&vv[i] = *(const float4*)&kp[64 + i];
#pragma unroll
      for (int i = 0; i < 16; ++i) acc[i] = acc[i] * sc + p * vv[i];
      m = mn;
    }
  }
  float inv = 1.f / l;
  float* op = att + ((size_t)br * NPIX + pix) * 64 + h * 16;
#pragma unroll
  for (int i = 0; i < 16; ++i) op[i] = acc[i] * inv;
}

// ---------------- Kernel 3: NAT proj + residual ----------------
// grid = 3 * 392
__global__ __launch_bounds__(256) void k_nat_proj(
    const float* __restrict__ att, const float* __restrict__ pw,
    const float* __restrict__ pb, const float* __restrict__ x,
    float* __restrict__ x1) {
  __shared__ float sW[64 * 64];
  __shared__ float sA[32][65];
  __shared__ float sPB[64];
  int br = blockIdx.x / 392;
  int grp = blockIdx.x % 392;
  int tid = threadIdx.x;
  for (int i = tid * 4; i < 4096; i += 1024)
    *(float4*)&sW[i] = *(const float4*)&pw[br * 4096 + i];
  if (tid < 64) sPB[tid] = pb[br * 64 + tid];
  for (int i = tid * 4; i < 32 * 64; i += 1024) {
    int p = i >> 6, c = i & 63;
    float4 v = *(const float4*)&att[((size_t)br * NPIX + grp * 32 + p) * 64 + c];
    sA[p][c] = v.x; sA[p][c + 1] = v.y; sA[p][c + 2] = v.z; sA[p][c + 3] = v.w;
  }
  __syncthreads();
  int pl = tid >> 3, o0 = (tid & 7) * 8;
  float acc[8];
#pragma unroll
  for (int j = 0; j < 8; ++j) acc[j] = sPB[o0 + j];
  for (int c = 0; c < 64; ++c) {
    float a = sA[pl][c];
    const float4* wr = (const float4*)&sW[c * 64 + o0];
#pragma unroll
    for (int j4 = 0; j4 < 2; ++j4) {
      float4 w = wr[j4];
      acc[4 * j4 + 0] = fmaf(a, w.x, acc[4 * j4 + 0]);
      acc[4 * j4 + 1] = fmaf(a, w.y, acc[4 * j4 + 1]);
      acc[4 * j4 + 2] = fmaf(a, w.z, acc[4 * j4 + 2]);
      acc[4 * j4 + 3] = fmaf(a, w.w, acc[4 * j4 + 3]);
    }
  }
  int pg = grp * 32 + pl;
  const float* xr = x + (size_t)pg * 256 + br * 64 + o0;
  float* op = x1 + ((size_t)br * NPIX + pg) * 64 + o0;
#pragma unroll
  for (int j = 0; j < 8; ++j) op[j] = acc[j] + xr[j];
}

// ---------------- Kernel 4: GA LN1 + 2x2 mean pool ----------------
// one wave per pooled token; grid = 3136/4 = 784 blocks
__global__ __launch_bounds__(256) void k_ga_pool(
    const float* __restrict__ x, const float* __restrict__ g,
    const float* __restrict__ bta, float* __restrict__ xa) {
  int t = blockIdx.x * 4 + (threadIdx.x >> 6);
  int lane = threadIdx.x & 63;
  int b = t / 784, rem = t % 784, hp = rem / 28, wp = rem % 28;
  float gg = g[lane], bb = bta[lane];
  float s = 0.f;
#pragma unroll
  for (int dy = 0; dy < 2; ++dy)
#pragma unroll
    for (int dx = 0; dx < 2; ++dx) {
      int pix = b * 3136 + (hp * 2 + dy) * 56 + (wp * 2 + dx);
      float v = x[(size_t)pix * 256 + 192 + lane];
      float s1 = wsum(v), s2 = wsum(v * v);
      float m = s1 * (1.f / 64.f);
      float var = s2 * (1.f / 64.f) - m * m;
      s += (v - m) * rsqrtf(var + 1e-5f) * gg + bb;
    }
  xa[(size_t)t * 64 + lane] = 0.25f * s;
}

// ---------------- Kernel 5: GA QKV GEMM ----------------
// grid = 3136/32 = 98 blocks
__global__ __launch_bounds__(256) void k_ga_qkv(
    const float* __restrict__ xa, const float* __restrict__ w,
    const float* __restrict__ bias, float* __restrict__ qkv) {
  __shared__ float sW[64 * 192];
  __shared__ float sB[192];
  __shared__ float sX[32][65];
  int grp = blockIdx.x;
  int tid = threadIdx.x;
  for (int i = tid * 4; i < 64 * 192; i += 1024)
    *(float4*)&sW[i] = *(const float4*)&w[i];
  if (tid < 192) sB[tid] = bias[tid];
  for (int i = tid * 4; i < 32 * 64; i += 1024) {
    int p = i >> 6, c = i & 63;
    float4 v = *(const float4*)&xa[(size_t)(grp * 32 + p) * 64 + c];
    sX[p][c] = v.x; sX[p][c + 1] = v.y; sX[p][c + 2] = v.z; sX[p][c + 3] = v.w;
  }
  __syncthreads();
  int pl = tid >> 3, o0 = (tid & 7) * 24;
  float acc[24];
#pragma unroll
  for (int j = 0; j < 24; ++j) acc[j] = sB[o0 + j];
  for (int c = 0; c < 64; ++c) {
    float a = sX[pl][c];
    const float4* wr = (const float4*)&sW[c * 192 + o0];
#pragma unroll
    for (int j4 = 0; j4 < 6; ++j4) {
      float4 w4 = wr[j4];
      acc[4 * j4 + 0] = fmaf(a, w4.x, acc[4 * j4 + 0]);
      acc[4 * j4 + 1] = fmaf(a, w4.y, acc[4 * j4 + 1]);
      acc[4 * j4 + 2] = fmaf(a, w4.z, acc[4 * j4 + 2]);
      acc[4 * j4 + 3] = fmaf(a, w4.w, acc[4 * j4 + 3]);
    }
  }
  float* op = qkv + (size_t)(grp * 32 + pl) * 192 + o0;
#pragma unroll
  for (int j = 0; j < 24; ++j) {
    float v = acc[j];
    if (o0 + j < 64) v *= 0.25f;
    op[j] = v;
  }
}

// ---------------- Kernel 6: GA full attention + upsample + residual ----------------
// grid = B*HEADS*13 = 208 blocks; K/V staged bf16 in LDS (50KB)
__global__ __launch_bounds__(256) void k_ga_attn(
    const float* __restrict__ qkv, const float* __restrict__ x,
    float* __restrict__ x1g) {
  __shared__ uint32_t sK[784 * 8];
  __shared__ uint32_t sV[784 * 8];
  int blk = blockIdx.x;
  int chunk = blk % 13;
  int bh = blk / 13;
  int h = bh & 3, b = bh >> 2;
  int tid = threadIdx.x;
  for (int i = tid; i < 784 * 4; i += 256) {
    int n = i >> 2, seg = (i & 3) * 4;
    const float* base = qkv + (size_t)(b * 784 + n) * 192 + h * 16 + seg;
    float4 kv = *(const float4*)&base[64];
    float4 vv = *(const float4*)&base[128];
    sK[n * 8 + seg / 2 + 0] = packbf(kv.x, kv.y);
    sK[n * 8 + seg / 2 + 1] = packbf(kv.z, kv.w);
    sV[n * 8 + seg / 2 + 0] = packbf(vv.x, vv.y);
    sV[n * 8 + seg / 2 + 1] = packbf(vv.z, vv.w);
  }
  __syncthreads();
  int rl = tid >> 2, s = tid & 3;
  int r = chunk * 64 + rl;
  float m = -1e30f, l = 0.f;
  float acc[16];
#pragma unroll
  for (int i = 0; i < 16; ++i) acc[i] = 0.f;
  if (r < 784) {
    const float* qp = qkv + (size_t)(b * 784 + r) * 192 + h * 16;
    float q[16];
#pragma unroll
    for (int i = 0; i < 16; i += 4) *(float4*)&q[i] = *(const float4*)&qp[i];
    for (int n = s; n < 784; n += 4) {
      const uint32_t* kp = &sK[n * 8];
      float sd = 0.f;
#pragma unroll
      for (int i = 0; i < 8; ++i) {
        uint32_t u = kp[i];
        sd = fmaf(q[2 * i], bflo(u), sd);
        sd = fmaf(q[2 * i + 1], bfhi(u), sd);
      }
      float mn = fmaxf(m, sd);
      float sc = __expf(m - mn);
      float p = __expf(sd - mn);
      l = l * sc + p;
      const uint32_t* vp = &sV[n * 8];
#pragma unroll
      for (int i = 0; i < 8; ++i) {
        uint32_t u = vp[i];
        acc[2 * i] = acc[2 * i] * sc + p * bflo(u);
        acc[2 * i + 1] = acc[2 * i + 1] * sc + p * bfhi(u);
      }
      m = mn;
    }
  }
  // merge 4 key-partials per row (lanes differ in bits 0..1)
#pragma unroll
  for (int mask = 1; mask <= 2; mask <<= 1) {
    float m2 = __shfl_xor(m, mask, 64);
    float l2 = __shfl_xor(l, mask, 64);
    float mn = fmaxf(m, m2);
    float a = __expf(m - mn), b2 = __expf(m2 - mn);
    l = l * a + l2 * b2;
#pragma unroll
    for (int i = 0; i < 16; ++i) {
      float o2 = __shfl_xor(acc[i], mask, 64);
      acc[i] = acc[i] * a + o2 * b2;
    }
    m = mn;
  }
  if (s == 0 && r < 784) {
    float inv = 1.f / l;
    int hp = r / 28, wp = r % 28;
#pragma unroll
    for (int dy = 0; dy < 2; ++dy)
#pragma unroll
      for (int dx = 0; dx < 2; ++dx) {
        int pix = b * 3136 + (hp * 2 + dy) * 56 + (wp * 2 + dx);
#pragma unroll
        for (int i = 0; i < 16; ++i) {
          int ch = h * 16 + i;
          x1g[(size_t)pix * 64 + ch] = x[(size_t)pix * 256 + 192 + ch] + acc[i] * inv;
        }
      }
  }
}

// ---------------- Kernel 7: LN2 + MLP + residual (all 4 branches) ----------------
// grid = 4 * 784 blocks, 16 pixels each
__global__ __launch_bounds__(256) void k_mlp(
    const float* __restrict__ x1, const float* __restrict__ nat_ln2_g,
    const float* __restrict__ nat_ln2_b, const float* __restrict__ nat_f1w,
    const float* __restrict__ nat_f1b, const float* __restrict__ nat_f2w,
    const float* __restrict__ nat_f2b, const float* __restrict__ ga_ln2_g,
    const float* __restrict__ ga_ln2_b, const float* __restrict__ ga_f1w,
    const float* __restrict__ ga_f1b, const float* __restrict__ ga_f2w,
    const float* __restrict__ ga_f2b, float* __restrict__ out) {
  __shared__ float sXn[16][64];
  __shared__ float sH[16][256];
  int br = blockIdx.x / 784;
  int grp = blockIdx.x % 784;
  int H1 = (br < 3) ? 256 : 192;
  const float* W1 = (br < 3) ? nat_f1w + br * 64 * 256 : ga_f1w;
  const float* B1 = (br < 3) ? nat_f1b + br * 256 : ga_f1b;
  const float* W2 = (br < 3) ? nat_f2w + br * 256 * 64 : ga_f2w;
  const float* B2 = (br < 3) ? nat_f2b + br * 64 : ga_f2b;
  const float* G = (br < 3) ? nat_ln2_g + br * 64 : ga_ln2_g;
  const float* Bt = (br < 3) ? nat_ln2_b + br * 64 : ga_ln2_b;
  int tid = threadIdx.x, lane = tid & 63, wid = tid >> 6;
  const float* xin = x1 + ((size_t)br * NPIX + grp * 16) * 64;
  float g = G[lane], bb = Bt[lane];
#pragma unroll
  for (int i = 0; i < 4; ++i) {
    int p = wid * 4 + i;
    float v = xin[p * 64 + lane];
    float s1 = wsum(v), s2 = wsum(v * v);
    float m = s1 * (1.f / 64.f);
    float var = s2 * (1.f / 64.f) - m * m;
    sXn[p][lane] = (v - m) * rsqrtf(var + 1e-5f) * g + bb;
  }
  __syncthreads();
  // FC1: thread owns hidden unit j=tid for all 16 pixels
  if (tid < H1) {
    float hacc[16];
    float b1 = B1[tid];
#pragma unroll
    for (int p = 0; p < 16; ++p) hacc[p] = b1;
    for (int c = 0; c < 64; ++c) {
      float w = W1[c * H1 + tid];
#pragma unroll
      for (int p = 0; p < 16; ++p) hacc[p] = fmaf(sXn[p][c], w, hacc[p]);
    }
#pragma unroll
    for (int p = 0; p < 16; ++p) sH[p][tid] = gelu_exact(hacc[p]);
  }
  __syncthreads();
  // FC2: thread owns (o = tid&63) x 4 pixels (pg = tid>>6)
  int o = tid & 63, pg = tid >> 6;
  float oacc[4];
  float b2 = B2[o];
#pragma unroll
  for (int pp = 0; pp < 4; ++pp) oacc[pp] = b2;
  for (int j = 0; j < H1; ++j) {
    float w = W2[j * 64 + o];
#pragma unroll
    for (int pp = 0; pp < 4; ++pp) oacc[pp] = fmaf(sH[pg * 4 + pp][j], w, oacc[pp]);
  }
#pragma unroll
  for (int pp = 0; pp < 4; ++pp) {
    int p = pg * 4 + pp;
    int pix = grp * 16 + p;
    out[(size_t)pix * 256 + br * 64 + o] = xin[p * 64 + o] + oacc[pp];
  }
}

}  // namespace

extern "C" void kernel_launch(void* const* d_in, const int* in_sizes, int n_in,
                              void* d_out, int out_size, void* d_ws, size_t ws_size,
                              hipStream_t stream) {
  const float* x = (const float*)d_in[0];
  const float* nat_ln1_g = (const float*)d_in[1];
  const float* nat_ln1_b = (const float*)d_in[2];
  const float* nat_qkv_w = (const float*)d_in[3];
  const float* nat_qkv_b = (const float*)d_in[4];
  const float* nat_rpb = (const float*)d_in[5];
  const float* nat_proj_w = (const float*)d_in[6];
  const float* nat_proj_b = (const float*)d_in[7];
  const float* nat_ln2_g = (const float*)d_in[8];
  const float* nat_ln2_b = (const float*)d_in[9];
  const float* nat_fc1_w = (const float*)d_in[10];
  const float* nat_fc1_b = (const float*)d_in[11];
  const float* nat_fc2_w = (const float*)d_in[12];
  const float* nat_fc2_b = (const float*)d_in[13];
  const float* ga_ln1_g = (const float*)d_in[14];
  const float* ga_ln1_b = (const float*)d_in[15];
  const float* ga_qkv_w = (const float*)d_in[16];
  const float* ga_qkv_b = (const float*)d_in[17];
  const float* ga_ln2_g = (const float*)d_in[18];
  const float* ga_ln2_b = (const float*)d_in[19];
  const float* ga_fc1_w = (const float*)d_in[20];
  const float* ga_fc1_b = (const float*)d_in[21];
  const float* ga_fc2_w = (const float*)d_in[22];
  const float* ga_fc2_b = (const float*)d_in[23];

  float* ws = (float*)d_ws;
  float* qkv_nat = ws;                   // 3*12544*192 = 7,225,344
  float* att     = ws + 7225344;         // 3*12544*64  = 2,408,448
  float* x1      = ws + 9633792;         // 4*12544*64  = 3,211,264
  float* xa      = ws + 12845056;        // 3136*64     = 200,704
  float* qkv_ga  = ws + 13045760;        // 3136*192    = 602,112
  // total ws: 13,647,872 floats = 54.6 MB

  k_nat_ln_qkv<<<dim3(1176), dim3(256), 0, stream>>>(x, nat_ln1_g, nat_ln1_b,
                                                     nat_qkv_w, nat_qkv_b, qkv_nat);
  k_ga_pool<<<dim3(784), dim3(256), 0, stream>>>(x, ga_ln1_g, ga_ln1_b, xa);
  k_ga_qkv<<<dim3(98), dim3(256), 0, stream>>>(xa, ga_qkv_w, ga_qkv_b, qkv_ga);
  k_nat_attn<<<dim3(588), dim3(256), 0, stream>>>(qkv_nat, nat_rpb, att);
  k_nat_proj<<<dim3(1176), dim3(256), 0, stream>>>(att, nat_proj_w, nat_proj_b, x, x1);
  k_ga_attn<<<dim3(208), dim3(256), 0, stream>>>(qkv_ga, x, x1 + (size_t)3 * NPIX * 64);
  k_mlp<<<dim3(3136), dim3(256), 0, stream>>>(x1, nat_ln2_g, nat_ln2_b, nat_fc1_w,
                                              nat_fc1_b, nat_fc2_w, nat_fc2_b,
                                              ga_ln2_g, ga_ln2_b, ga_fc1_w, ga_fc1_b,
                                              ga_fc2_w, ga_fc2_b, (float*)d_out);
}

// Round 2
// 207.379 us; speedup vs baseline: 1.4810x; 1.4810x over previous
//
#include <hip/hip_runtime.h>
#include <hip/hip_bf16.h>
#include <cstdint>

namespace {

constexpr int NPIX = 12544;   // 4*56*56

typedef __attribute__((ext_vector_type(8))) short bf16x8;
typedef __attribute__((ext_vector_type(4))) float f32x4;

__device__ __forceinline__ float wsum(float v) {
#pragma unroll
  for (int m = 32; m; m >>= 1) v += __shfl_xor(v, m, 64);
  return v;
}

__device__ __forceinline__ uint16_t f2bf(float f) {
  uint32_t u = __builtin_bit_cast(uint32_t, f);
  u += 0x7fffu + ((u >> 16) & 1u);
  return (uint16_t)(u >> 16);
}
__device__ __forceinline__ uint32_t packbf(float a, float b) {
  return (uint32_t)f2bf(a) | ((uint32_t)f2bf(b) << 16);
}
__device__ __forceinline__ float bflo(uint32_t u) { return __builtin_bit_cast(float, u << 16); }
__device__ __forceinline__ float bfhi(uint32_t u) { return __builtin_bit_cast(float, u & 0xffff0000u); }

__device__ __forceinline__ float gelu_fast(float v) {
  float u = 0.7978845608028654f * (v + 0.044715f * v * v * v);
  float e = __expf(2.f * u);
  float th = 1.f - 2.f * __builtin_amdgcn_rcpf(e + 1.f);
  return 0.5f * v * (1.f + th);
}

// ---------------- Prep: convert+transpose all weights to bf16 ----------------
// Layout in wT (ushort):
//   natQkvT [3][192][72]  @0        (41472)
//   natProjT[3][64][72]   @41472    (13824)
//   natF1T  [3][256][72]  @55296    (55296)
//   natF2T  [3][64][264]  @110592   (50688)
//   gaQkvT  [192][72]     @161280   (13824)   (unused this round, reserved)
//   gaF1T   [192][72]     @175104   (13824)
//   gaF2T   [64][200]     @188928   (12800)
// total 201728 ushorts
__global__ __launch_bounds__(256) void k_prep(
    const float* __restrict__ nqkv, const float* __restrict__ nproj,
    const float* __restrict__ nf1, const float* __restrict__ nf2,
    const float* __restrict__ gqkv, const float* __restrict__ gf1,
    const float* __restrict__ gf2, ushort* __restrict__ wT) {
  int t = blockIdx.x * 256 + threadIdx.x;
  if (t >= 201728) return;
  int i = t;
  if (i < 41472) {  // natQkvT <- nat_qkv_w [3][64][192]
    int br = i / 13824, r = i % 13824, n = r / 72, k = r % 72;
    wT[t] = k < 64 ? f2bf(nqkv[(br * 64 + k) * 192 + n]) : (ushort)0;
    return;
  }
  i -= 41472;
  if (i < 13824) {  // natProjT <- nat_proj_w [3][64][64]
    int br = i / 4608, r = i % 4608, n = r / 72, k = r % 72;
    wT[t] = k < 64 ? f2bf(nproj[(br * 64 + k) * 64 + n]) : (ushort)0;
    return;
  }
  i -= 13824;
  if (i < 55296) {  // natF1T <- nat_fc1_w [3][64][256]
    int br = i / 18432, r = i % 18432, n = r / 72, k = r % 72;
    wT[t] = k < 64 ? f2bf(nf1[(br * 64 + k) * 256 + n]) : (ushort)0;
    return;
  }
  i -= 55296;
  if (i < 50688) {  // natF2T <- nat_fc2_w [3][256][64]
    int br = i / 16896, r = i % 16896, n = r / 264, k = r % 264;
    wT[t] = k < 256 ? f2bf(nf2[(br * 256 + k) * 64 + n]) : (ushort)0;
    return;
  }
  i -= 50688;
  if (i < 13824) {  // gaQkvT <- ga_qkv_w [64][192]
    int n = i / 72, k = i % 72;
    wT[t] = k < 64 ? f2bf(gqkv[k * 192 + n]) : (ushort)0;
    return;
  }
  i -= 13824;
  if (i < 13824) {  // gaF1T <- ga_fc1_w [64][192]
    int n = i / 72, k = i % 72;
    wT[t] = k < 64 ? f2bf(gf1[k * 192 + n]) : (ushort)0;
    return;
  }
  i -= 13824;
  {  // gaF2T <- ga_fc2_w [192][64]
    int n = i / 200, k = i % 200;
    wT[t] = k < 192 ? f2bf(gf2[k * 64 + n]) : (ushort)0;
  }
}

// ---------------- Kernel 1: NAT LN1 + QKV GEMM via MFMA ----------------
// grid = 3 * 196 blocks, 64 pixels per block
__global__ __launch_bounds__(256) void k_nat_ln_qkv(
    const float* __restrict__ x, const float* __restrict__ ln_g,
    const float* __restrict__ ln_b, const ushort* __restrict__ wT,
    const float* __restrict__ qkv_b, float* __restrict__ qkv_out) {
  __shared__ __align__(16) ushort sA[64 * 72];
  __shared__ __align__(16) ushort sB[192 * 72];
  int br = blockIdx.x / 196, grp = blockIdx.x % 196;
  int tid = threadIdx.x, lane = tid & 63, wid = tid >> 6;
  // stage B (13824 ushorts = 1728 uint4)
  const uint4* srcB = (const uint4*)(wT + br * 13824);
  uint4* dstB = (uint4*)sB;
  for (int i = tid; i < 1728; i += 256) dstB[i] = srcB[i];
  // LN: each wave 16 pixels, lane = channel
  float g = ln_g[br * 64 + lane], bb = ln_b[br * 64 + lane];
#pragma unroll
  for (int i = 0; i < 16; ++i) {
    int pl = wid * 16 + i;
    float v = x[(size_t)(grp * 64 + pl) * 256 + br * 64 + lane];
    float s1 = wsum(v), s2 = wsum(v * v);
    float m = s1 * (1.f / 64.f);
    float var = s2 * (1.f / 64.f) - m * m;
    sA[pl * 72 + lane] = f2bf((v - m) * rsqrtf(var + 1e-5f) * g + bb);
  }
  __syncthreads();
  int lr = lane & 15, lk = (lane >> 4) * 8;
  int m0 = wid * 16;
  bf16x8 a0 = *(const bf16x8*)&sA[(m0 + lr) * 72 + lk];
  bf16x8 a1 = *(const bf16x8*)&sA[(m0 + lr) * 72 + 32 + lk];
  int r0 = m0 + (lane >> 4) * 4;
#pragma unroll
  for (int nt = 0; nt < 12; ++nt) {
    int n0 = nt * 16;
    bf16x8 b0 = *(const bf16x8*)&sB[(n0 + lr) * 72 + lk];
    bf16x8 b1 = *(const bf16x8*)&sB[(n0 + lr) * 72 + 32 + lk];
    f32x4 acc = {0.f, 0.f, 0.f, 0.f};
    acc = __builtin_amdgcn_mfma_f32_16x16x32_bf16(a0, b0, acc, 0, 0, 0);
    acc = __builtin_amdgcn_mfma_f32_16x16x32_bf16(a1, b1, acc, 0, 0, 0);
    int col = n0 + lr;
    float bias = qkv_b[br * 192 + col];
    float scale = col < 64 ? 0.25f : 1.0f;
    float* op = qkv_out + ((size_t)br * NPIX + grp * 64 + r0) * 192 + col;
#pragma unroll
    for (int r = 0; r < 4; ++r) op[r * 192] = (acc[r] + bias) * scale;
  }
}

// ---------------- Kernel 2: NAT neighborhood attention (writes bf16) -------
__global__ __launch_bounds__(256) void k_nat_attn(
    const float* __restrict__ qkv, const float* __restrict__ rpb,
    ushort* __restrict__ att) {
  int gid = blockIdx.x * 256 + threadIdx.x;
  int br = gid / (NPIX * 4);
  int t = gid % (NPIX * 4);
  int pix = t >> 2, h = t & 3;
  int b = pix / 3136;
  int y = (pix / 56) % 56, xx = pix % 56;
  int sy = min(max(y - 3, 0), 49), sx = min(max(xx - 3, 0), 49);
  const float* qp = qkv + ((size_t)br * NPIX + pix) * 192 + h * 16;
  float q[16];
#pragma unroll
  for (int i = 0; i < 16; i += 4) *(float4*)&q[i] = *(const float4*)&qp[i];
  const float* rp = rpb + (br * 4 + h) * 169 + (sy - y + 6) * 13 + (sx - xx + 6);
  float m = -1e30f, l = 0.f;
  float acc[16];
#pragma unroll
  for (int i = 0; i < 16; ++i) acc[i] = 0.f;
  for (int a = 0; a < 7; ++a) {
    const float* kbase =
        qkv + ((size_t)br * NPIX + (b * 3136 + (sy + a) * 56 + sx)) * 192 + 64 + h * 16;
    for (int c = 0; c < 7; ++c) {
      const float* kp = kbase + c * 192;
      float kk[16];
#pragma unroll
      for (int i = 0; i < 16; i += 4) *(float4*)&kk[i] = *(const float4*)&kp[i];
      float s = 0.f;
#pragma unroll
      for (int i = 0; i < 16; ++i) s = fmaf(q[i], kk[i], s);
      s += rp[a * 13 + c];
      float mn = fmaxf(m, s);
      float sc = __expf(m - mn);
      float p = __expf(s - mn);
      l = l * sc + p;
      float vv[16];
#pragma unroll
      for (int i = 0; i < 16; i += 4) *(float4*)&vv[i] = *(const float4*)&kp[64 + i];
#pragma unroll
      for (int i = 0; i < 16; ++i) acc[i] = acc[i] * sc + p * vv[i];
      m = mn;
    }
  }
  float inv = 1.f / l;
  uint32_t* op = (uint32_t*)(att + ((size_t)br * NPIX + pix) * 64 + h * 16);
#pragma unroll
  for (int i = 0; i < 8; ++i) op[i] = packbf(acc[2 * i] * inv, acc[2 * i + 1] * inv);
}

// ---------------- Kernel 3: NAT proj + residual via MFMA ----------------
// grid = 3 * 196 blocks, 64 pixels per block
__global__ __launch_bounds__(256) void k_nat_proj(
    const ushort* __restrict__ att, const ushort* __restrict__ wT,
    const float* __restrict__ pb, const float* __restrict__ x,
    float* __restrict__ x1) {
  __shared__ __align__(16) ushort sA[64 * 72];
  __shared__ __align__(16) ushort sB[64 * 72];
  int br = blockIdx.x / 196, grp = blockIdx.x % 196;
  int tid = threadIdx.x, lane = tid & 63, wid = tid >> 6;
  // stage B: natProjT at 41472 + br*4608, 4608 ushorts = 576 uint4
  const uint4* srcB = (const uint4*)(wT + 41472 + br * 4608);
  uint4* dstB = (uint4*)sB;
  for (int i = tid; i < 576; i += 256) dstB[i] = srcB[i];
  // stage A: att rows (64 pix x 64 ch bf16, 8 uint4 per row) -> stride 72
  const uint4* srcA = (const uint4*)(att + ((size_t)br * NPIX + grp * 64) * 64);
  for (int i = tid; i < 512; i += 256) {
    int row = i >> 3, seg = i & 7;
    *(uint4*)&sA[row * 72 + seg * 8] = srcA[i];
  }
  __syncthreads();
  int lr = lane & 15, lk = (lane >> 4) * 8;
  int m0 = wid * 16;
  bf16x8 a0 = *(const bf16x8*)&sA[(m0 + lr) * 72 + lk];
  bf16x8 a1 = *(const bf16x8*)&sA[(m0 + lr) * 72 + 32 + lk];
  int r0 = m0 + (lane >> 4) * 4;
#pragma unroll
  for (int nt = 0; nt < 4; ++nt) {
    int n0 = nt * 16;
    bf16x8 b0 = *(const bf16x8*)&sB[(n0 + lr) * 72 + lk];
    bf16x8 b1 = *(const bf16x8*)&sB[(n0 + lr) * 72 + 32 + lk];
    f32x4 acc = {0.f, 0.f, 0.f, 0.f};
    acc = __builtin_amdgcn_mfma_f32_16x16x32_bf16(a0, b0, acc, 0, 0, 0);
    acc = __builtin_amdgcn_mfma_f32_16x16x32_bf16(a1, b1, acc, 0, 0, 0);
    int col = n0 + lr;
    float bias = pb[br * 64 + col];
#pragma unroll
    for (int r = 0; r < 4; ++r) {
      int pg = grp * 64 + r0 + r;
      x1[((size_t)br * NPIX + pg) * 64 + col] =
          acc[r] + bias + x[(size_t)pg * 256 + br * 64 + col];
    }
  }
}

// ---------------- Kernel 4: GA LN1 + 2x2 mean pool ----------------
__global__ __launch_bounds__(256) void k_ga_pool(
    const float* __restrict__ x, const float* __restrict__ g,
    const float* __restrict__ bta, float* __restrict__ xa) {
  int t = blockIdx.x * 4 + (threadIdx.x >> 6);
  int lane = threadIdx.x & 63;
  int b = t / 784, rem = t % 784, hp = rem / 28, wp = rem % 28;
  float gg = g[lane], bb = bta[lane];
  float s = 0.f;
#pragma unroll
  for (int dy = 0; dy < 2; ++dy)
#pragma unroll
    for (int dx = 0; dx < 2; ++dx) {
      int pix = b * 3136 + (hp * 2 + dy) * 56 + (wp * 2 + dx);
      float v = x[(size_t)pix * 256 + 192 + lane];
      float s1 = wsum(v), s2 = wsum(v * v);
      float m = s1 * (1.f / 64.f);
      float var = s2 * (1.f / 64.f) - m * m;
      s += (v - m) * rsqrtf(var + 1e-5f) * gg + bb;
    }
  xa[(size_t)t * 64 + lane] = 0.25f * s;
}

// ---------------- Kernel 5: GA QKV GEMM (fp32, small) ----------------
__global__ __launch_bounds__(256) void k_ga_qkv(
    const float* __restrict__ xa, const float* __restrict__ w,
    const float* __restrict__ bias, float* __restrict__ qkv) {
  __shared__ float sW[64 * 192];
  __shared__ float sB[192];
  __shared__ float sX[32][65];
  int grp = blockIdx.x;
  int tid = threadIdx.x;
  for (int i = tid * 4; i < 64 * 192; i += 1024)
    *(float4*)&sW[i] = *(const float4*)&w[i];
  if (tid < 192) sB[tid] = bias[tid];
  for (int i = tid * 4; i < 32 * 64; i += 1024) {
    int p = i >> 6, c = i & 63;
    float4 v = *(const float4*)&xa[(size_t)(grp * 32 + p) * 64 + c];
    sX[p][c] = v.x; sX[p][c + 1] = v.y; sX[p][c + 2] = v.z; sX[p][c + 3] = v.w;
  }
  __syncthreads();
  int pl = tid >> 3, o0 = (tid & 7) * 24;
  float acc[24];
#pragma unroll
  for (int j = 0; j < 24; ++j) acc[j] = sB[o0 + j];
  for (int c = 0; c < 64; ++c) {
    float a = sX[pl][c];
    const float4* wr = (const float4*)&sW[c * 192 + o0];
#pragma unroll
    for (int j4 = 0; j4 < 6; ++j4) {
      float4 w4 = wr[j4];
      acc[4 * j4 + 0] = fmaf(a, w4.x, acc[4 * j4 + 0]);
      acc[4 * j4 + 1] = fmaf(a, w4.y, acc[4 * j4 + 1]);
      acc[4 * j4 + 2] = fmaf(a, w4.z, acc[4 * j4 + 2]);
      acc[4 * j4 + 3] = fmaf(a, w4.w, acc[4 * j4 + 3]);
    }
  }
  float* op = qkv + (size_t)(grp * 32 + pl) * 192 + o0;
#pragma unroll
  for (int j = 0; j < 24; ++j) {
    float v = acc[j];
    if (o0 + j < 64) v *= 0.25f;
    op[j] = v;
  }
}

// ---------------- Kernel 6: GA full attention + upsample + residual -------
__global__ __launch_bounds__(256) void k_ga_attn(
    const float* __restrict__ qkv, const float* __restrict__ x,
    float* __restrict__ x1g) {
  __shared__ uint32_t sK[784 * 8];
  __shared__ uint32_t sV[784 * 8];
  int blk = blockIdx.x;
  int chunk = blk % 13;
  int bh = blk / 13;
  int h = bh & 3, b = bh >> 2;
  int tid = threadIdx.x;
  for (int i = tid; i < 784 * 4; i += 256) {
    int n = i >> 2, seg = (i & 3) * 4;
    const float* base = qkv + (size_t)(b * 784 + n) * 192 + h * 16 + seg;
    float4 kv = *(const float4*)&base[64];
    float4 vv = *(const float4*)&base[128];
    sK[n * 8 + seg / 2 + 0] = packbf(kv.x, kv.y);
    sK[n * 8 + seg / 2 + 1] = packbf(kv.z, kv.w);
    sV[n * 8 + seg / 2 + 0] = packbf(vv.x, vv.y);
    sV[n * 8 + seg / 2 + 1] = packbf(vv.z, vv.w);
  }
  __syncthreads();
  int rl = tid >> 2, s = tid & 3;
  int r = chunk * 64 + rl;
  float m = -1e30f, l = 0.f;
  float acc[16];
#pragma unroll
  for (int i = 0; i < 16; ++i) acc[i] = 0.f;
  if (r < 784) {
    const float* qp = qkv + (size_t)(b * 784 + r) * 192 + h * 16;
    float q[16];
#pragma unroll
    for (int i = 0; i < 16; i += 4) *(float4*)&q[i] = *(const float4*)&qp[i];
    for (int n = s; n < 784; n += 4) {
      const uint32_t* kp = &sK[n * 8];
      float sd = 0.f;
#pragma unroll
      for (int i = 0; i < 8; ++i) {
        uint32_t u = kp[i];
        sd = fmaf(q[2 * i], bflo(u), sd);
        sd = fmaf(q[2 * i + 1], bfhi(u), sd);
      }
      float mn = fmaxf(m, sd);
      float sc = __expf(m - mn);
      float p = __expf(sd - mn);
      l = l * sc + p;
      const uint32_t* vp = &sV[n * 8];
#pragma unroll
      for (int i = 0; i < 8; ++i) {
        uint32_t u = vp[i];
        acc[2 * i] = acc[2 * i] * sc + p * bflo(u);
        acc[2 * i + 1] = acc[2 * i + 1] * sc + p * bfhi(u);
      }
      m = mn;
    }
  }
#pragma unroll
  for (int mask = 1; mask <= 2; mask <<= 1) {
    float m2 = __shfl_xor(m, mask, 64);
    float l2 = __shfl_xor(l, mask, 64);
    float mn = fmaxf(m, m2);
    float a = __expf(m - mn), b2 = __expf(m2 - mn);
    l = l * a + l2 * b2;
#pragma unroll
    for (int i = 0; i < 16; ++i) {
      float o2 = __shfl_xor(acc[i], mask, 64);
      acc[i] = acc[i] * a + o2 * b2;
    }
    m = mn;
  }
  if (s == 0 && r < 784) {
    float inv = 1.f / l;
    int hp = r / 28, wp = r % 28;
#pragma unroll
    for (int dy = 0; dy < 2; ++dy)
#pragma unroll
      for (int dx = 0; dx < 2; ++dx) {
        int pix = b * 3136 + (hp * 2 + dy) * 56 + (wp * 2 + dx);
#pragma unroll
        for (int i = 0; i < 16; ++i) {
          int ch = h * 16 + i;
          x1g[(size_t)pix * 64 + ch] = x[(size_t)pix * 256 + 192 + ch] + acc[i] * inv;
        }
      }
  }
}

// ---------------- Kernel 7: LN2 + MLP + residual via MFMA ----------------
// NAT: grid = 3*392 (32 pixels/block). GA: grid = 392.
template <bool NAT>
__global__ __launch_bounds__(256) void k_mlp(
    const float* __restrict__ x1, const float* __restrict__ nat_ln2_g,
    const float* __restrict__ nat_ln2_b, const ushort* __restrict__ wT,
    const float* __restrict__ nat_f1b, const float* __restrict__ nat_f2b,
    const float* __restrict__ ga_ln2_g, const float* __restrict__ ga_ln2_b,
    const float* __restrict__ ga_f1b, const float* __restrict__ ga_f2b,
    float* __restrict__ out) {
  constexpr int H1 = NAT ? 256 : 192;
  constexpr int K2P = NAT ? 264 : 200;
  constexpr int KB = H1 / 32;  // k-blocks for FC2: 8 or 6
  constexpr int SW = NAT ? 256 * 72 : 192 * 72;
  __shared__ __align__(16) ushort sX[32 * 72];
  __shared__ __align__(16) ushort sH[32 * K2P];
  __shared__ __align__(16) ushort sW[SW];
  int br = NAT ? (int)(blockIdx.x / 392) : 3;
  int grp = blockIdx.x % 392;
  int tid = threadIdx.x, lane = tid & 63, wid = tid >> 6;
  const ushort* W1 = NAT ? wT + 55296 + br * 18432 : wT + 175104;
  const ushort* W2 = NAT ? wT + 110592 + br * 16896 : wT + 188928;
  const float* B1 = NAT ? nat_f1b + br * 256 : ga_f1b;
  const float* B2 = NAT ? nat_f2b + br * 64 : ga_f2b;
  const float* G = NAT ? nat_ln2_g + br * 64 : ga_ln2_g;
  const float* Bt = NAT ? nat_ln2_b + br * 64 : ga_ln2_b;
  const float* xin = x1 + ((size_t)br * NPIX + grp * 32) * 64;
  // stage W1 [H1][72]
  constexpr int NW1 = H1 * 9;  // uint4 count
  for (int i = tid; i < NW1; i += 256) ((uint4*)sW)[i] = ((const uint4*)W1)[i];
  // LN: 4 waves x 8 pixels
  float g = G[lane], bb = Bt[lane];
#pragma unroll
  for (int i = 0; i < 8; ++i) {
    int pl = wid * 8 + i;
    float v = xin[pl * 64 + lane];
    float s1 = wsum(v), s2 = wsum(v * v);
    float m = s1 * (1.f / 64.f);
    float var = s2 * (1.f / 64.f) - m * m;
    sX[pl * 72 + lane] = f2bf((v - m) * rsqrtf(var + 1e-5f) * g + bb);
  }
  __syncthreads();
  int lr = lane & 15, lk = (lane >> 4) * 8;
  int m0 = (wid & 1) * 16;
  int r0 = (lane >> 4) * 4;
  bf16x8 a0 = *(const bf16x8*)&sX[(m0 + lr) * 72 + lk];
  bf16x8 a1 = *(const bf16x8*)&sX[(m0 + lr) * 72 + 32 + lk];
  // FC1 + GELU
#pragma unroll
  for (int t2 = 0; t2 < H1 / 32; ++t2) {
    int n0 = ((wid >> 1) + 2 * t2) * 16;
    bf16x8 b0 = *(const bf16x8*)&sW[(n0 + lr) * 72 + lk];
    bf16x8 b1 = *(const bf16x8*)&sW[(n0 + lr) * 72 + 32 + lk];
    f32x4 acc = {0.f, 0.f, 0.f, 0.f};
    acc = __builtin_amdgcn_mfma_f32_16x16x32_bf16(a0, b0, acc, 0, 0, 0);
    acc = __builtin_amdgcn_mfma_f32_16x16x32_bf16(a1, b1, acc, 0, 0, 0);
    int col = n0 + lr;
    float b1v = B1[col];
#pragma unroll
    for (int r = 0; r < 4; ++r)
      sH[(m0 + r0 + r) * K2P + col] = f2bf(gelu_fast(acc[r] + b1v));
  }
  __syncthreads();
  // stage W2 [64][K2P] over sW (B1 reads done)
  constexpr int NW2 = 64 * K2P / 8;
  for (int i = tid; i < NW2; i += 256) ((uint4*)sW)[i] = ((const uint4*)W2)[i];
  __syncthreads();
  // FC2
  bf16x8 af[KB];
#pragma unroll
  for (int kb = 0; kb < KB; ++kb)
    af[kb] = *(const bf16x8*)&sH[(m0 + lr) * K2P + kb * 32 + lk];
#pragma unroll
  for (int u = 0; u < 2; ++u) {
    int n0 = ((wid >> 1) + 2 * u) * 16;
    f32x4 acc = {0.f, 0.f, 0.f, 0.f};
#pragma unroll
    for (int kb = 0; kb < KB; ++kb) {
      bf16x8 bf = *(const bf16x8*)&sW[(n0 + lr) * K2P + kb * 32 + lk];
      acc = __builtin_amdgcn_mfma_f32_16x16x32_bf16(af[kb], bf, acc, 0, 0, 0);
    }
    int col = n0 + lr;
    float b2v = B2[col];
#pragma unroll
    for (int r = 0; r < 4; ++r) {
      int p = m0 + r0 + r;
      int pix = grp * 32 + p;
      out[(size_t)pix * 256 + br * 64 + col] = xin[p * 64 + col] + acc[r] + b2v;
    }
  }
}

}  // namespace

extern "C" void kernel_launch(void* const* d_in, const int* in_sizes, int n_in,
                              void* d_out, int out_size, void* d_ws, size_t ws_size,
                              hipStream_t stream) {
  const float* x = (const float*)d_in[0];
  const float* nat_ln1_g = (const float*)d_in[1];
  const float* nat_ln1_b = (const float*)d_in[2];
  const float* nat_qkv_w = (const float*)d_in[3];
  const float* nat_qkv_b = (const float*)d_in[4];
  const float* nat_rpb = (const float*)d_in[5];
  const float* nat_proj_w = (const float*)d_in[6];
  const float* nat_proj_b = (const float*)d_in[7];
  const float* nat_ln2_g = (const float*)d_in[8];
  const float* nat_ln2_b = (const float*)d_in[9];
  const float* nat_fc1_w = (const float*)d_in[10];
  const float* nat_fc1_b = (const float*)d_in[11];
  const float* nat_fc2_w = (const float*)d_in[12];
  const float* nat_fc2_b = (const float*)d_in[13];
  const float* ga_ln1_g = (const float*)d_in[14];
  const float* ga_ln1_b = (const float*)d_in[15];
  const float* ga_qkv_w = (const float*)d_in[16];
  const float* ga_qkv_b = (const float*)d_in[17];
  const float* ga_ln2_g = (const float*)d_in[18];
  const float* ga_ln2_b = (const float*)d_in[19];
  const float* ga_fc1_w = (const float*)d_in[20];
  const float* ga_fc1_b = (const float*)d_in[21];
  const float* ga_fc2_w = (const float*)d_in[22];
  const float* ga_fc2_b = (const float*)d_in[23];

  uint8_t* w8 = (uint8_t*)d_ws;
  float*  qkv_nat = (float*)w8;                       // 28,901,376 B
  ushort* att     = (ushort*)(w8 + 28901376);         //  4,816,896 B
  float*  x1      = (float*)(w8 + 33718272);          // 12,845,056 B
  float*  xa      = (float*)(w8 + 46563328);          //    802,816 B
  float*  qkv_ga  = (float*)(w8 + 47366144);          //  2,408,448 B
  ushort* wT      = (ushort*)(w8 + 49774592);         //    403,456 B
  // total ~50.2 MB

  k_prep<<<dim3(789), dim3(256), 0, stream>>>(nat_qkv_w, nat_proj_w, nat_fc1_w,
                                              nat_fc2_w, ga_qkv_w, ga_fc1_w,
                                              ga_fc2_w, wT);
  k_nat_ln_qkv<<<dim3(588), dim3(256), 0, stream>>>(x, nat_ln1_g, nat_ln1_b, wT,
                                                    nat_qkv_b, qkv_nat);
  k_ga_pool<<<dim3(784), dim3(256), 0, stream>>>(x, ga_ln1_g, ga_ln1_b, xa);
  k_ga_qkv<<<dim3(98), dim3(256), 0, stream>>>(xa, ga_qkv_w, ga_qkv_b, qkv_ga);
  k_nat_attn<<<dim3(588), dim3(256), 0, stream>>>(qkv_nat, nat_rpb, att);
  k_nat_proj<<<dim3(588), dim3(256), 0, stream>>>(att, wT, nat_proj_b, x, x1);
  k_ga_attn<<<dim3(208), dim3(256), 0, stream>>>(qkv_ga, x, x1 + (size_t)3 * NPIX * 64);
  k_mlp<true><<<dim3(1176), dim3(256), 0, stream>>>(
      x1, nat_ln2_g, nat_ln2_b, wT, nat_fc1_b, nat_fc2_b, ga_ln2_g, ga_ln2_b,
      ga_fc1_b, ga_fc2_b, (float*)d_out);
  k_mlp<false><<<dim3(392), dim3(256), 0, stream>>>(
      x1, nat_ln2_g, nat_ln2_b, wT, nat_fc1_b, nat_fc2_b, ga_ln2_g, ga_ln2_b,
      ga_fc1_b, ga_fc2_b, (float*)d_out);
}

// Round 3
// 154.759 us; speedup vs baseline: 1.9845x; 1.3400x over previous
//
#include <hip/hip_runtime.h>
#include <hip/hip_bf16.h>
#include <cstdint>

namespace {

constexpr int NPIX = 12544;   // 4*56*56

typedef __attribute__((ext_vector_type(8))) short bf16x8;
typedef __attribute__((ext_vector_type(4))) float f32x4;

__device__ __forceinline__ float wsum(float v) {
#pragma unroll
  for (int m = 32; m; m >>= 1) v += __shfl_xor(v, m, 64);
  return v;
}

__device__ __forceinline__ uint16_t f2bf(float f) {
  uint32_t u = __builtin_bit_cast(uint32_t, f);
  u += 0x7fffu + ((u >> 16) & 1u);
  return (uint16_t)(u >> 16);
}
__device__ __forceinline__ uint32_t packbf(float a, float b) {
  return (uint32_t)f2bf(a) | ((uint32_t)f2bf(b) << 16);
}
__device__ __forceinline__ float bflo(uint32_t u) { return __builtin_bit_cast(float, u << 16); }
__device__ __forceinline__ float bfhi(uint32_t u) { return __builtin_bit_cast(float, u & 0xffff0000u); }

__device__ __forceinline__ float gelu_fast(float v) {
  float u = 0.7978845608028654f * (v + 0.044715f * v * v * v);
  float e = __expf(2.f * u);
  float th = 1.f - 2.f * __builtin_amdgcn_rcpf(e + 1.f);
  return 0.5f * v * (1.f + th);
}

// ---------------- Prep: convert+transpose all weights to bf16 ----------------
__global__ __launch_bounds__(256) void k_prep(
    const float* __restrict__ nqkv, const float* __restrict__ nproj,
    const float* __restrict__ nf1, const float* __restrict__ nf2,
    const float* __restrict__ gqkv, const float* __restrict__ gf1,
    const float* __restrict__ gf2, ushort* __restrict__ wT) {
  int t = blockIdx.x * 256 + threadIdx.x;
  if (t >= 201728) return;
  int i = t;
  if (i < 41472) {  // natQkvT [3][192][72]
    int br = i / 13824, r = i % 13824, n = r / 72, k = r % 72;
    wT[t] = k < 64 ? f2bf(nqkv[(br * 64 + k) * 192 + n]) : (ushort)0;
    return;
  }
  i -= 41472;
  if (i < 13824) {  // natProjT [3][64][72]
    int br = i / 4608, r = i % 4608, n = r / 72, k = r % 72;
    wT[t] = k < 64 ? f2bf(nproj[(br * 64 + k) * 64 + n]) : (ushort)0;
    return;
  }
  i -= 13824;
  if (i < 55296) {  // natF1T [3][256][72]
    int br = i / 18432, r = i % 18432, n = r / 72, k = r % 72;
    wT[t] = k < 64 ? f2bf(nf1[(br * 64 + k) * 256 + n]) : (ushort)0;
    return;
  }
  i -= 55296;
  if (i < 50688) {  // natF2T [3][64][264]
    int br = i / 16896, r = i % 16896, n = r / 264, k = r % 264;
    wT[t] = k < 256 ? f2bf(nf2[(br * 256 + k) * 64 + n]) : (ushort)0;
    return;
  }
  i -= 50688;
  if (i < 13824) {  // gaQkvT [192][72]
    int n = i / 72, k = i % 72;
    wT[t] = k < 64 ? f2bf(gqkv[k * 192 + n]) : (ushort)0;
    return;
  }
  i -= 13824;
  if (i < 13824) {  // gaF1T [192][72]
    int n = i / 72, k = i % 72;
    wT[t] = k < 64 ? f2bf(gf1[k * 192 + n]) : (ushort)0;
    return;
  }
  i -= 13824;
  {  // gaF2T [64][200]
    int n = i / 200, k = i % 200;
    wT[t] = k < 192 ? f2bf(gf2[k * 64 + n]) : (ushort)0;
  }
}

// ---------------- Kernel 1: NAT LN1 + QKV GEMM via MFMA ----------------
// q -> fp32 (pre-scaled), K/V -> bf16 [pix][128]
__global__ __launch_bounds__(256) void k_nat_ln_qkv(
    const float* __restrict__ x, const float* __restrict__ ln_g,
    const float* __restrict__ ln_b, const ushort* __restrict__ wT,
    const float* __restrict__ qkv_b, float* __restrict__ qn,
    ushort* __restrict__ kvn) {
  __shared__ __align__(16) ushort sA[64 * 72];
  __shared__ __align__(16) ushort sB[192 * 72];
  int br = blockIdx.x / 196, grp = blockIdx.x % 196;
  int tid = threadIdx.x, lane = tid & 63, wid = tid >> 6;
  const uint4* srcB = (const uint4*)(wT + br * 13824);
  uint4* dstB = (uint4*)sB;
  for (int i = tid; i < 1728; i += 256) dstB[i] = srcB[i];
  float g = ln_g[br * 64 + lane], bb = ln_b[br * 64 + lane];
#pragma unroll
  for (int i = 0; i < 16; ++i) {
    int pl = wid * 16 + i;
    float v = x[(size_t)(grp * 64 + pl) * 256 + br * 64 + lane];
    float s1 = wsum(v), s2 = wsum(v * v);
    float m = s1 * (1.f / 64.f);
    float var = s2 * (1.f / 64.f) - m * m;
    sA[pl * 72 + lane] = f2bf((v - m) * rsqrtf(var + 1e-5f) * g + bb);
  }
  __syncthreads();
  int lr = lane & 15, lk = (lane >> 4) * 8;
  int m0 = wid * 16;
  bf16x8 a0 = *(const bf16x8*)&sA[(m0 + lr) * 72 + lk];
  bf16x8 a1 = *(const bf16x8*)&sA[(m0 + lr) * 72 + 32 + lk];
  int r0 = m0 + (lane >> 4) * 4;
#pragma unroll
  for (int nt = 0; nt < 12; ++nt) {
    int n0 = nt * 16;
    bf16x8 b0 = *(const bf16x8*)&sB[(n0 + lr) * 72 + lk];
    bf16x8 b1 = *(const bf16x8*)&sB[(n0 + lr) * 72 + 32 + lk];
    f32x4 acc = {0.f, 0.f, 0.f, 0.f};
    acc = __builtin_amdgcn_mfma_f32_16x16x32_bf16(a0, b0, acc, 0, 0, 0);
    acc = __builtin_amdgcn_mfma_f32_16x16x32_bf16(a1, b1, acc, 0, 0, 0);
    int col = n0 + lr;
    float bias = qkv_b[br * 192 + col];
    if (nt < 4) {
      float* op = qn + ((size_t)br * NPIX + grp * 64 + r0) * 64 + col;
#pragma unroll
      for (int r = 0; r < 4; ++r) op[r * 64] = (acc[r] + bias) * 0.25f;
    } else {
      ushort* op = kvn + ((size_t)br * NPIX + grp * 64 + r0) * 128 + (col - 64);
#pragma unroll
      for (int r = 0; r < 4; ++r) op[r * 128] = f2bf(acc[r] + bias);
    }
  }
}

// ---------------- Kernel 2: NAT neighborhood attention (LDS-tiled) -------
// one block per (branch, batch, 8x8 pixel tile); halo K/V staged in LDS
__global__ __launch_bounds__(256) void k_nat_attn(
    const float* __restrict__ qn, const ushort* __restrict__ kvn,
    const float* __restrict__ rpb, ushort* __restrict__ att) {
  __shared__ __align__(16) ushort sKV[196 * 136];  // 53,312 B -> 3 blocks/CU
  int bi = blockIdx.x;
  int br = bi / 196, rem = bi % 196;
  int b = rem / 49, t = rem % 49;
  int y0 = (t / 7) * 8, x0 = (t % 7) * 8;
  int hy = min(max(y0 - 3, 0), 42), hx = min(max(x0 - 3, 0), 42);
  int tid = threadIdx.x;
  const ushort* kvbase = kvn + ((size_t)br * NPIX + b * 3136) * 128;
  for (int i = tid; i < 3136; i += 256) {
    int p = i >> 4, c = i & 15;
    int py = p / 14, px = p % 14;
    int gp = (hy + py) * 56 + (hx + px);
    uint4 v = *(const uint4*)&kvbase[(size_t)gp * 128 + c * 8];
    *(uint4*)&sKV[p * 136 + c * 8] = v;
  }
  __syncthreads();
  int pl = tid & 63, h = tid >> 6;
  int ly = pl >> 3, lx = pl & 7;
  int y = y0 + ly, xg = x0 + lx;
  int sy = min(max(y - 3, 0), 49), sx = min(max(xg - 3, 0), 49);
  int by = sy - hy, bx = sx - hx;
  int gpix = b * 3136 + y * 56 + xg;
  const float* qp = qn + ((size_t)br * NPIX + gpix) * 64 + h * 16;
  float q[16];
#pragma unroll
  for (int i = 0; i < 16; i += 4) *(float4*)&q[i] = *(const float4*)&qp[i];
  const float* rp = rpb + (br * 4 + h) * 169 + (sy - y + 6) * 13 + (sx - xg + 6);
  float m = -1e30f, l = 0.f;
  float acc[16];
#pragma unroll
  for (int i = 0; i < 16; ++i) acc[i] = 0.f;
  for (int a = 0; a < 7; ++a) {
    const uint32_t* krow =
        (const uint32_t*)&sKV[((by + a) * 14 + bx) * 136 + h * 16];
    float bias_r[7];
#pragma unroll
    for (int c = 0; c < 7; ++c) bias_r[c] = rp[a * 13 + c];
    for (int c = 0; c < 7; ++c) {
      const uint32_t* kp = krow + c * 68;
      float sd = 0.f;
#pragma unroll
      for (int i = 0; i < 8; ++i) {
        uint32_t u = kp[i];
        sd = fmaf(q[2 * i], bflo(u), sd);
        sd = fmaf(q[2 * i + 1], bfhi(u), sd);
      }
      sd += bias_r[c];
      float mn = fmaxf(m, sd);
      float sc = __expf(m - mn);
      float p = __expf(sd - mn);
      l = l * sc + p;
#pragma unroll
      for (int i = 0; i < 8; ++i) {
        uint32_t u = kp[32 + i];
        acc[2 * i] = acc[2 * i] * sc + p * bflo(u);
        acc[2 * i + 1] = acc[2 * i + 1] * sc + p * bfhi(u);
      }
      m = mn;
    }
  }
  float inv = 1.f / l;
  uint32_t* op = (uint32_t*)(att + ((size_t)br * NPIX + gpix) * 64 + h * 16);
#pragma unroll
  for (int i = 0; i < 8; ++i) op[i] = packbf(acc[2 * i] * inv, acc[2 * i + 1] * inv);
}

// ---------------- Kernel 3: NAT proj + residual via MFMA ----------------
__global__ __launch_bounds__(256) void k_nat_proj(
    const ushort* __restrict__ att, const ushort* __restrict__ wT,
    const float* __restrict__ pb, const float* __restrict__ x,
    float* __restrict__ x1) {
  __shared__ __align__(16) ushort sA[64 * 72];
  __shared__ __align__(16) ushort sB[64 * 72];
  int br = blockIdx.x / 196, grp = blockIdx.x % 196;
  int tid = threadIdx.x, lane = tid & 63, wid = tid >> 6;
  const uint4* srcB = (const uint4*)(wT + 41472 + br * 4608);
  uint4* dstB = (uint4*)sB;
  for (int i = tid; i < 576; i += 256) dstB[i] = srcB[i];
  const uint4* srcA = (const uint4*)(att + ((size_t)br * NPIX + grp * 64) * 64);
  for (int i = tid; i < 512; i += 256) {
    int row = i >> 3, seg = i & 7;
    *(uint4*)&sA[row * 72 + seg * 8] = srcA[i];
  }
  __syncthreads();
  int lr = lane & 15, lk = (lane >> 4) * 8;
  int m0 = wid * 16;
  bf16x8 a0 = *(const bf16x8*)&sA[(m0 + lr) * 72 + lk];
  bf16x8 a1 = *(const bf16x8*)&sA[(m0 + lr) * 72 + 32 + lk];
  int r0 = m0 + (lane >> 4) * 4;
#pragma unroll
  for (int nt = 0; nt < 4; ++nt) {
    int n0 = nt * 16;
    bf16x8 b0 = *(const bf16x8*)&sB[(n0 + lr) * 72 + lk];
    bf16x8 b1 = *(const bf16x8*)&sB[(n0 + lr) * 72 + 32 + lk];
    f32x4 acc = {0.f, 0.f, 0.f, 0.f};
    acc = __builtin_amdgcn_mfma_f32_16x16x32_bf16(a0, b0, acc, 0, 0, 0);
    acc = __builtin_amdgcn_mfma_f32_16x16x32_bf16(a1, b1, acc, 0, 0, 0);
    int col = n0 + lr;
    float bias = pb[br * 64 + col];
#pragma unroll
    for (int r = 0; r < 4; ++r) {
      int pg = grp * 64 + r0 + r;
      x1[((size_t)br * NPIX + pg) * 64 + col] =
          acc[r] + bias + x[(size_t)pg * 256 + br * 64 + col];
    }
  }
}

// ---------------- Kernel 4: GA LN1 + 2x2 mean pool ----------------
__global__ __launch_bounds__(256) void k_ga_pool(
    const float* __restrict__ x, const float* __restrict__ g,
    const float* __restrict__ bta, float* __restrict__ xa) {
  int t = blockIdx.x * 4 + (threadIdx.x >> 6);
  int lane = threadIdx.x & 63;
  int b = t / 784, rem = t % 784, hp = rem / 28, wp = rem % 28;
  float gg = g[lane], bb = bta[lane];
  float s = 0.f;
#pragma unroll
  for (int dy = 0; dy < 2; ++dy)
#pragma unroll
    for (int dx = 0; dx < 2; ++dx) {
      int pix = b * 3136 + (hp * 2 + dy) * 56 + (wp * 2 + dx);
      float v = x[(size_t)pix * 256 + 192 + lane];
      float s1 = wsum(v), s2 = wsum(v * v);
      float m = s1 * (1.f / 64.f);
      float var = s2 * (1.f / 64.f) - m * m;
      s += (v - m) * rsqrtf(var + 1e-5f) * gg + bb;
    }
  xa[(size_t)t * 64 + lane] = 0.25f * s;
}

// ---------------- Kernel 5: GA QKV GEMM (fp32, small) ----------------
__global__ __launch_bounds__(256) void k_ga_qkv(
    const float* __restrict__ xa, const float* __restrict__ w,
    const float* __restrict__ bias, float* __restrict__ qkv) {
  __shared__ float sW[64 * 192];
  __shared__ float sB[192];
  __shared__ float sX[32][65];
  int grp = blockIdx.x;
  int tid = threadIdx.x;
  for (int i = tid * 4; i < 64 * 192; i += 1024)
    *(float4*)&sW[i] = *(const float4*)&w[i];
  if (tid < 192) sB[tid] = bias[tid];
  for (int i = tid * 4; i < 32 * 64; i += 1024) {
    int p = i >> 6, c = i & 63;
    float4 v = *(const float4*)&xa[(size_t)(grp * 32 + p) * 64 + c];
    sX[p][c] = v.x; sX[p][c + 1] = v.y; sX[p][c + 2] = v.z; sX[p][c + 3] = v.w;
  }
  __syncthreads();
  int pl = tid >> 3, o0 = (tid & 7) * 24;
  float acc[24];
#pragma unroll
  for (int j = 0; j < 24; ++j) acc[j] = sB[o0 + j];
  for (int c = 0; c < 64; ++c) {
    float a = sX[pl][c];
    const float4* wr = (const float4*)&sW[c * 192 + o0];
#pragma unroll
    for (int j4 = 0; j4 < 6; ++j4) {
      float4 w4 = wr[j4];
      acc[4 * j4 + 0] = fmaf(a, w4.x, acc[4 * j4 + 0]);
      acc[4 * j4 + 1] = fmaf(a, w4.y, acc[4 * j4 + 1]);
      acc[4 * j4 + 2] = fmaf(a, w4.z, acc[4 * j4 + 2]);
      acc[4 * j4 + 3] = fmaf(a, w4.w, acc[4 * j4 + 3]);
    }
  }
  float* op = qkv + (size_t)(grp * 32 + pl) * 192 + o0;
#pragma unroll
  for (int j = 0; j < 24; ++j) {
    float v = acc[j];
    if (o0 + j < 64) v *= 0.25f;
    op[j] = v;
  }
}

// ---------------- Kernel 6: GA full attention + upsample + residual -------
__global__ __launch_bounds__(256) void k_ga_attn(
    const float* __restrict__ qkv, const float* __restrict__ x,
    float* __restrict__ x1g) {
  __shared__ uint32_t sK[784 * 8];
  __shared__ uint32_t sV[784 * 8];
  int blk = blockIdx.x;
  int chunk = blk % 13;
  int bh = blk / 13;
  int h = bh & 3, b = bh >> 2;
  int tid = threadIdx.x;
  for (int i = tid; i < 784 * 4; i += 256) {
    int n = i >> 2, seg = (i & 3) * 4;
    const float* base = qkv + (size_t)(b * 784 + n) * 192 + h * 16 + seg;
    float4 kv = *(const float4*)&base[64];
    float4 vv = *(const float4*)&base[128];
    sK[n * 8 + seg / 2 + 0] = packbf(kv.x, kv.y);
    sK[n * 8 + seg / 2 + 1] = packbf(kv.z, kv.w);
    sV[n * 8 + seg / 2 + 0] = packbf(vv.x, vv.y);
    sV[n * 8 + seg / 2 + 1] = packbf(vv.z, vv.w);
  }
  __syncthreads();
  int rl = tid >> 2, s = tid & 3;
  int r = chunk * 64 + rl;
  float m = -1e30f, l = 0.f;
  float acc[16];
#pragma unroll
  for (int i = 0; i < 16; ++i) acc[i] = 0.f;
  if (r < 784) {
    const float* qp = qkv + (size_t)(b * 784 + r) * 192 + h * 16;
    float q[16];
#pragma unroll
    for (int i = 0; i < 16; i += 4) *(float4*)&q[i] = *(const float4*)&qp[i];
    for (int n = s; n < 784; n += 4) {
      const uint32_t* kp = &sK[n * 8];
      float sd = 0.f;
#pragma unroll
      for (int i = 0; i < 8; ++i) {
        uint32_t u = kp[i];
        sd = fmaf(q[2 * i], bflo(u), sd);
        sd = fmaf(q[2 * i + 1], bfhi(u), sd);
      }
      float mn = fmaxf(m, sd);
      float sc = __expf(m - mn);
      float p = __expf(sd - mn);
      l = l * sc + p;
      const uint32_t* vp = &sV[n * 8];
#pragma unroll
      for (int i = 0; i < 8; ++i) {
        uint32_t u = vp[i];
        acc[2 * i] = acc[2 * i] * sc + p * bflo(u);
        acc[2 * i + 1] = acc[2 * i + 1] * sc + p * bfhi(u);
      }
      m = mn;
    }
  }
#pragma unroll
  for (int mask = 1; mask <= 2; mask <<= 1) {
    float m2 = __shfl_xor(m, mask, 64);
    float l2 = __shfl_xor(l, mask, 64);
    float mn = fmaxf(m, m2);
    float a = __expf(m - mn), b2 = __expf(m2 - mn);
    l = l * a + l2 * b2;
#pragma unroll
    for (int i = 0; i < 16; ++i) {
      float o2 = __shfl_xor(acc[i], mask, 64);
      acc[i] = acc[i] * a + o2 * b2;
    }
    m = mn;
  }
  if (s == 0 && r < 784) {
    float inv = 1.f / l;
    int hp = r / 28, wp = r % 28;
#pragma unroll
    for (int dy = 0; dy < 2; ++dy)
#pragma unroll
      for (int dx = 0; dx < 2; ++dx) {
        int pix = b * 3136 + (hp * 2 + dy) * 56 + (wp * 2 + dx);
#pragma unroll
        for (int i = 0; i < 16; ++i) {
          int ch = h * 16 + i;
          x1g[(size_t)pix * 64 + ch] = x[(size_t)pix * 256 + 192 + ch] + acc[i] * inv;
        }
      }
  }
}

// ---------------- Kernel 7: LN2 + MLP + residual via MFMA ----------------
template <bool NAT>
__global__ __launch_bounds__(256) void k_mlp(
    const float* __restrict__ x1, const float* __restrict__ nat_ln2_g,
    const float* __restrict__ nat_ln2_b, const ushort* __restrict__ wT,
    const float* __restrict__ nat_f1b, const float* __restrict__ nat_f2b,
    const float* __restrict__ ga_ln2_g, const float* __restrict__ ga_ln2_b,
    const float* __restrict__ ga_f1b, const float* __restrict__ ga_f2b,
    float* __restrict__ out) {
  constexpr int H1 = NAT ? 256 : 192;
  constexpr int K2P = NAT ? 264 : 200;
  constexpr int KB = H1 / 32;
  constexpr int SW = NAT ? 256 * 72 : 192 * 72;
  __shared__ __align__(16) ushort sX[32 * 72];
  __shared__ __align__(16) ushort sH[32 * K2P];
  __shared__ __align__(16) ushort sW[SW];
  int br = NAT ? (int)(blockIdx.x / 392) : 3;
  int grp = blockIdx.x % 392;
  int tid = threadIdx.x, lane = tid & 63, wid = tid >> 6;
  const ushort* W1 = NAT ? wT + 55296 + br * 18432 : wT + 175104;
  const ushort* W2 = NAT ? wT + 110592 + br * 16896 : wT + 188928;
  const float* B1 = NAT ? nat_f1b + br * 256 : ga_f1b;
  const float* B2 = NAT ? nat_f2b + br * 64 : ga_f2b;
  const float* G = NAT ? nat_ln2_g + br * 64 : ga_ln2_g;
  const float* Bt = NAT ? nat_ln2_b + br * 64 : ga_ln2_b;
  const float* xin = x1 + ((size_t)br * NPIX + grp * 32) * 64;
  constexpr int NW1 = H1 * 9;
  for (int i = tid; i < NW1; i += 256) ((uint4*)sW)[i] = ((const uint4*)W1)[i];
  float g = G[lane], bb = Bt[lane];
#pragma unroll
  for (int i = 0; i < 8; ++i) {
    int pl = wid * 8 + i;
    float v = xin[pl * 64 + lane];
    float s1 = wsum(v), s2 = wsum(v * v);
    float m = s1 * (1.f / 64.f);
    float var = s2 * (1.f / 64.f) - m * m;
    sX[pl * 72 + lane] = f2bf((v - m) * rsqrtf(var + 1e-5f) * g + bb);
  }
  __syncthreads();
  int lr = lane & 15, lk = (lane >> 4) * 8;
  int m0 = (wid & 1) * 16;
  int r0 = (lane >> 4) * 4;
  bf16x8 a0 = *(const bf16x8*)&sX[(m0 + lr) * 72 + lk];
  bf16x8 a1 = *(const bf16x8*)&sX[(m0 + lr) * 72 + 32 + lk];
#pragma unroll
  for (int t2 = 0; t2 < H1 / 32; ++t2) {
    int n0 = ((wid >> 1) + 2 * t2) * 16;
    bf16x8 b0 = *(const bf16x8*)&sW[(n0 + lr) * 72 + lk];
    bf16x8 b1 = *(const bf16x8*)&sW[(n0 + lr) * 72 + 32 + lk];
    f32x4 acc = {0.f, 0.f, 0.f, 0.f};
    acc = __builtin_amdgcn_mfma_f32_16x16x32_bf16(a0, b0, acc, 0, 0, 0);
    acc = __builtin_amdgcn_mfma_f32_16x16x32_bf16(a1, b1, acc, 0, 0, 0);
    int col = n0 + lr;
    float b1v = B1[col];
#pragma unroll
    for (int r = 0; r < 4; ++r)
      sH[(m0 + r0 + r) * K2P + col] = f2bf(gelu_fast(acc[r] + b1v));
  }
  __syncthreads();
  constexpr int NW2 = 64 * K2P / 8;
  for (int i = tid; i < NW2; i += 256) ((uint4*)sW)[i] = ((const uint4*)W2)[i];
  __syncthreads();
  bf16x8 af[KB];
#pragma unroll
  for (int kb = 0; kb < KB; ++kb)
    af[kb] = *(const bf16x8*)&sH[(m0 + lr) * K2P + kb * 32 + lk];
#pragma unroll
  for (int u = 0; u < 2; ++u) {
    int n0 = ((wid >> 1) + 2 * u) * 16;
    f32x4 acc = {0.f, 0.f, 0.f, 0.f};
#pragma unroll
    for (int kb = 0; kb < KB; ++kb) {
      bf16x8 bf = *(const bf16x8*)&sW[(n0 + lr) * K2P + kb * 32 + lk];
      acc = __builtin_amdgcn_mfma_f32_16x16x32_bf16(af[kb], bf, acc, 0, 0, 0);
    }
    int col = n0 + lr;
    float b2v = B2[col];
#pragma unroll
    for (int r = 0; r < 4; ++r) {
      int p = m0 + r0 + r;
      int pix = grp * 32 + p;
      out[(size_t)pix * 256 + br * 64 + col] = xin[p * 64 + col] + acc[r] + b2v;
    }
  }
}

}  // namespace

extern "C" void kernel_launch(void* const* d_in, const int* in_sizes, int n_in,
                              void* d_out, int out_size, void* d_ws, size_t ws_size,
                              hipStream_t stream) {
  const float* x = (const float*)d_in[0];
  const float* nat_ln1_g = (const float*)d_in[1];
  const float* nat_ln1_b = (const float*)d_in[2];
  const float* nat_qkv_w = (const float*)d_in[3];
  const float* nat_qkv_b = (const float*)d_in[4];
  const float* nat_rpb = (const float*)d_in[5];
  const float* nat_proj_w = (const float*)d_in[6];
  const float* nat_proj_b = (const float*)d_in[7];
  const float* nat_ln2_g = (const float*)d_in[8];
  const float* nat_ln2_b = (const float*)d_in[9];
  const float* nat_fc1_w = (const float*)d_in[10];
  const float* nat_fc1_b = (const float*)d_in[11];
  const float* nat_fc2_w = (const float*)d_in[12];
  const float* nat_fc2_b = (const float*)d_in[13];
  const float* ga_ln1_g = (const float*)d_in[14];
  const float* ga_ln1_b = (const float*)d_in[15];
  const float* ga_qkv_w = (const float*)d_in[16];
  const float* ga_qkv_b = (const float*)d_in[17];
  const float* ga_ln2_g = (const float*)d_in[18];
  const float* ga_ln2_b = (const float*)d_in[19];
  const float* ga_fc1_w = (const float*)d_in[20];
  const float* ga_fc1_b = (const float*)d_in[21];
  const float* ga_fc2_w = (const float*)d_in[22];
  const float* ga_fc2_b = (const float*)d_in[23];

  uint8_t* w8 = (uint8_t*)d_ws;
  float*  qn     = (float*)w8;                        //  9,633,792 B
  ushort* kvn    = (ushort*)(w8 + 9633792);           //  9,633,792 B
  ushort* att    = (ushort*)(w8 + 19267584);          //  4,816,896 B
  float*  x1     = (float*)(w8 + 24084480);           // 12,845,056 B
  float*  xa     = (float*)(w8 + 36929536);           //    802,816 B
  float*  qkv_ga = (float*)(w8 + 37732352);           //  2,408,448 B
  ushort* wT     = (ushort*)(w8 + 40140800);          //    403,456 B

  k_prep<<<dim3(789), dim3(256), 0, stream>>>(nat_qkv_w, nat_proj_w, nat_fc1_w,
                                              nat_fc2_w, ga_qkv_w, ga_fc1_w,
                                              ga_fc2_w, wT);
  k_nat_ln_qkv<<<dim3(588), dim3(256), 0, stream>>>(x, nat_ln1_g, nat_ln1_b, wT,
                                                    nat_qkv_b, qn, kvn);
  k_ga_pool<<<dim3(784), dim3(256), 0, stream>>>(x, ga_ln1_g, ga_ln1_b, xa);
  k_ga_qkv<<<dim3(98), dim3(256), 0, stream>>>(xa, ga_qkv_w, ga_qkv_b, qkv_ga);
  k_nat_attn<<<dim3(588), dim3(256), 0, stream>>>(qn, kvn, nat_rpb, att);
  k_nat_proj<<<dim3(588), dim3(256), 0, stream>>>(att, wT, nat_proj_b, x, x1);
  k_ga_attn<<<dim3(208), dim3(256), 0, stream>>>(qkv_ga, x, x1 + (size_t)3 * NPIX * 64);
  k_mlp<true><<<dim3(1176), dim3(256), 0, stream>>>(
      x1, nat_ln2_g, nat_ln2_b, wT, nat_fc1_b, nat_fc2_b, ga_ln2_g, ga_ln2_b,
      ga_fc1_b, ga_fc2_b, (float*)d_out);
  k_mlp<false><<<dim3(392), dim3(256), 0, stream>>>(
      x1, nat_ln2_g, nat_ln2_b, wT, nat_fc1_b, nat_fc2_b, ga_ln2_g, ga_ln2_b,
      ga_fc1_b, ga_fc2_b, (float*)d_out);
}

// Round 5
// 131.233 us; speedup vs baseline: 2.3403x; 1.1793x over previous
//
#include <hip/hip_runtime.h>
#include <hip/hip_bf16.h>
#include <cstdint>

namespace {

constexpr int NPIX = 12544;   // 4*56*56

typedef __attribute__((ext_vector_type(8))) short bf16x8;
typedef __attribute__((ext_vector_type(4))) float f32x4;
typedef __attribute__((ext_vector_type(16))) float f32x16;

__device__ __forceinline__ float wsum(float v) {
#pragma unroll
  for (int m = 32; m; m >>= 1) v += __shfl_xor(v, m, 64);
  return v;
}

__device__ __forceinline__ uint16_t f2bf(float f) {
  uint32_t u = __builtin_bit_cast(uint32_t, f);
  u += 0x7fffu + ((u >> 16) & 1u);
  return (uint16_t)(u >> 16);
}
__device__ __forceinline__ uint32_t packbf(float a, float b) {
  return (uint32_t)f2bf(a) | ((uint32_t)f2bf(b) << 16);
}
__device__ __forceinline__ float bflo(uint32_t u) { return __builtin_bit_cast(float, u << 16); }
__device__ __forceinline__ float bfhi(uint32_t u) { return __builtin_bit_cast(float, u & 0xffff0000u); }

__device__ __forceinline__ float gelu_fast(float v) {
  float u = 0.7978845608028654f * (v + 0.044715f * v * v * v);
  float e = __expf(2.f * u);
  float th = 1.f - 2.f * __builtin_amdgcn_rcpf(e + 1.f);
  return 0.5f * v * (1.f + th);
}

// ---------------- Prep: convert+transpose all weights to bf16 ----------------
__global__ __launch_bounds__(256) void k_prep(
    const float* __restrict__ nqkv, const float* __restrict__ nproj,
    const float* __restrict__ nf1, const float* __restrict__ nf2,
    const float* __restrict__ gqkv, const float* __restrict__ gf1,
    const float* __restrict__ gf2, ushort* __restrict__ wT) {
  int t = blockIdx.x * 256 + threadIdx.x;
  if (t >= 201728) return;
  int i = t;
  if (i < 41472) {  // natQkvT [3][192][72]
    int br = i / 13824, r = i % 13824, n = r / 72, k = r % 72;
    wT[t] = k < 64 ? f2bf(nqkv[(br * 64 + k) * 192 + n]) : (ushort)0;
    return;
  }
  i -= 41472;
  if (i < 13824) {  // natProjT [3][64][72]
    int br = i / 4608, r = i % 4608, n = r / 72, k = r % 72;
    wT[t] = k < 64 ? f2bf(nproj[(br * 64 + k) * 64 + n]) : (ushort)0;
    return;
  }
  i -= 13824;
  if (i < 55296) {  // natF1T [3][256][72]
    int br = i / 18432, r = i % 18432, n = r / 72, k = r % 72;
    wT[t] = k < 64 ? f2bf(nf1[(br * 64 + k) * 256 + n]) : (ushort)0;
    return;
  }
  i -= 55296;
  if (i < 50688) {  // natF2T [3][64][264]
    int br = i / 16896, r = i % 16896, n = r / 264, k = r % 264;
    wT[t] = k < 256 ? f2bf(nf2[(br * 256 + k) * 64 + n]) : (ushort)0;
    return;
  }
  i -= 50688;
  if (i < 13824) {  // gaQkvT [192][72] (reserved)
    int n = i / 72, k = i % 72;
    wT[t] = k < 64 ? f2bf(gqkv[k * 192 + n]) : (ushort)0;
    return;
  }
  i -= 13824;
  if (i < 13824) {  // gaF1T [192][72]
    int n = i / 72, k = i % 72;
    wT[t] = k < 64 ? f2bf(gf1[k * 192 + n]) : (ushort)0;
    return;
  }
  i -= 13824;
  {  // gaF2T [64][200]
    int n = i / 200, k = i % 200;
    wT[t] = k < 192 ? f2bf(gf2[k * 64 + n]) : (ushort)0;
  }
}

// ---------------- Kernel 1: NAT LN1 + QKV GEMM via MFMA ----------------
__global__ __launch_bounds__(256) void k_nat_ln_qkv(
    const float* __restrict__ x, const float* __restrict__ ln_g,
    const float* __restrict__ ln_b, const ushort* __restrict__ wT,
    const float* __restrict__ qkv_b, float* __restrict__ qn,
    ushort* __restrict__ kvn) {
  __shared__ __align__(16) ushort sA[64 * 72];
  __shared__ __align__(16) ushort sB[192 * 72];
  int br = blockIdx.x / 196, grp = blockIdx.x % 196;
  int tid = threadIdx.x, lane = tid & 63, wid = tid >> 6;
  const uint4* srcB = (const uint4*)(wT + br * 13824);
  uint4* dstB = (uint4*)sB;
  for (int i = tid; i < 1728; i += 256) dstB[i] = srcB[i];
  float g = ln_g[br * 64 + lane], bb = ln_b[br * 64 + lane];
#pragma unroll
  for (int i = 0; i < 16; ++i) {
    int pl = wid * 16 + i;
    float v = x[(size_t)(grp * 64 + pl) * 256 + br * 64 + lane];
    float s1 = wsum(v), s2 = wsum(v * v);
    float m = s1 * (1.f / 64.f);
    float var = s2 * (1.f / 64.f) - m * m;
    sA[pl * 72 + lane] = f2bf((v - m) * rsqrtf(var + 1e-5f) * g + bb);
  }
  __syncthreads();
  int lr = lane & 15, lk = (lane >> 4) * 8;
  int m0 = wid * 16;
  bf16x8 a0 = *(const bf16x8*)&sA[(m0 + lr) * 72 + lk];
  bf16x8 a1 = *(const bf16x8*)&sA[(m0 + lr) * 72 + 32 + lk];
  int r0 = m0 + (lane >> 4) * 4;
#pragma unroll
  for (int nt = 0; nt < 12; ++nt) {
    int n0 = nt * 16;
    bf16x8 b0 = *(const bf16x8*)&sB[(n0 + lr) * 72 + lk];
    bf16x8 b1 = *(const bf16x8*)&sB[(n0 + lr) * 72 + 32 + lk];
    f32x4 acc = {0.f, 0.f, 0.f, 0.f};
    acc = __builtin_amdgcn_mfma_f32_16x16x32_bf16(a0, b0, acc, 0, 0, 0);
    acc = __builtin_amdgcn_mfma_f32_16x16x32_bf16(a1, b1, acc, 0, 0, 0);
    int col = n0 + lr;
    float bias = qkv_b[br * 192 + col];
    if (nt < 4) {
      float* op = qn + ((size_t)br * NPIX + grp * 64 + r0) * 64 + col;
#pragma unroll
      for (int r = 0; r < 4; ++r) op[r * 64] = (acc[r] + bias) * 0.25f;
    } else {
      ushort* op = kvn + ((size_t)br * NPIX + grp * 64 + r0) * 128 + (col - 64);
#pragma unroll
      for (int r = 0; r < 4; ++r) op[r * 128] = f2bf(acc[r] + bias);
    }
  }
}

// ---------------- Kernel 2: NAT neighborhood attention (LDS-tiled) -------
__global__ __launch_bounds__(256) void k_nat_attn(
    const float* __restrict__ qn, const ushort* __restrict__ kvn,
    const float* __restrict__ rpb, ushort* __restrict__ att) {
  __shared__ __align__(16) ushort sKV[196 * 136];
  int bi = blockIdx.x;
  int br = bi / 196, rem = bi % 196;
  int b = rem / 49, t = rem % 49;
  int y0 = (t / 7) * 8, x0 = (t % 7) * 8;
  int hy = min(max(y0 - 3, 0), 42), hx = min(max(x0 - 3, 0), 42);
  int tid = threadIdx.x;
  const ushort* kvbase = kvn + ((size_t)br * NPIX + b * 3136) * 128;
  for (int i = tid; i < 3136; i += 256) {
    int p = i >> 4, c = i & 15;
    int py = p / 14, px = p % 14;
    int gp = (hy + py) * 56 + (hx + px);
    uint4 v = *(const uint4*)&kvbase[(size_t)gp * 128 + c * 8];
    *(uint4*)&sKV[p * 136 + c * 8] = v;
  }
  __syncthreads();
  int pl = tid & 63, h = tid >> 6;
  int ly = pl >> 3, lx = pl & 7;
  int y = y0 + ly, xg = x0 + lx;
  int sy = min(max(y - 3, 0), 49), sx = min(max(xg - 3, 0), 49);
  int by = sy - hy, bx = sx - hx;
  int gpix = b * 3136 + y * 56 + xg;
  const float* qp = qn + ((size_t)br * NPIX + gpix) * 64 + h * 16;
  float q[16];
#pragma unroll
  for (int i = 0; i < 16; i += 4) *(float4*)&q[i] = *(const float4*)&qp[i];
  const float* rp = rpb + (br * 4 + h) * 169 + (sy - y + 6) * 13 + (sx - xg + 6);
  float m = -1e30f, l = 0.f;
  float acc[16];
#pragma unroll
  for (int i = 0; i < 16; ++i) acc[i] = 0.f;
  for (int a = 0; a < 7; ++a) {
    const uint32_t* krow =
        (const uint32_t*)&sKV[((by + a) * 14 + bx) * 136 + h * 16];
    float bias_r[7];
#pragma unroll
    for (int c = 0; c < 7; ++c) bias_r[c] = rp[a * 13 + c];
    for (int c = 0; c < 7; ++c) {
      const uint32_t* kp = krow + c * 68;
      float sd = 0.f;
#pragma unroll
      for (int i = 0; i < 8; ++i) {
        uint32_t u = kp[i];
        sd = fmaf(q[2 * i], bflo(u), sd);
        sd = fmaf(q[2 * i + 1], bfhi(u), sd);
      }
      sd += bias_r[c];
      float mn = fmaxf(m, sd);
      float sc = __expf(m - mn);
      float p = __expf(sd - mn);
      l = l * sc + p;
#pragma unroll
      for (int i = 0; i < 8; ++i) {
        uint32_t u = kp[32 + i];
        acc[2 * i] = acc[2 * i] * sc + p * bflo(u);
        acc[2 * i + 1] = acc[2 * i + 1] * sc + p * bfhi(u);
      }
      m = mn;
    }
  }
  float inv = 1.f / l;
  uint32_t* op = (uint32_t*)(att + ((size_t)br * NPIX + gpix) * 64 + h * 16);
#pragma unroll
  for (int i = 0; i < 8; ++i) op[i] = packbf(acc[2 * i] * inv, acc[2 * i + 1] * inv);
}

// ---------------- Kernel 3: NAT proj + residual via MFMA ----------------
__global__ __launch_bounds__(256) void k_nat_proj(
    const ushort* __restrict__ att, const ushort* __restrict__ wT,
    const float* __restrict__ pb, const float* __restrict__ x,
    float* __restrict__ x1) {
  __shared__ __align__(16) ushort sA[64 * 72];
  __shared__ __align__(16) ushort sB[64 * 72];
  int br = blockIdx.x / 196, grp = blockIdx.x % 196;
  int tid = threadIdx.x, lane = tid & 63, wid = tid >> 6;
  const uint4* srcB = (const uint4*)(wT + 41472 + br * 4608);
  uint4* dstB = (uint4*)sB;
  for (int i = tid; i < 576; i += 256) dstB[i] = srcB[i];
  const uint4* srcA = (const uint4*)(att + ((size_t)br * NPIX + grp * 64) * 64);
  for (int i = tid; i < 512; i += 256) {
    int row = i >> 3, seg = i & 7;
    *(uint4*)&sA[row * 72 + seg * 8] = srcA[i];
  }
  __syncthreads();
  int lr = lane & 15, lk = (lane >> 4) * 8;
  int m0 = wid * 16;
  bf16x8 a0 = *(const bf16x8*)&sA[(m0 + lr) * 72 + lk];
  bf16x8 a1 = *(const bf16x8*)&sA[(m0 + lr) * 72 + 32 + lk];
  int r0 = m0 + (lane >> 4) * 4;
#pragma unroll
  for (int nt = 0; nt < 4; ++nt) {
    int n0 = nt * 16;
    bf16x8 b0 = *(const bf16x8*)&sB[(n0 + lr) * 72 + lk];
    bf16x8 b1 = *(const bf16x8*)&sB[(n0 + lr) * 72 + 32 + lk];
    f32x4 acc = {0.f, 0.f, 0.f, 0.f};
    acc = __builtin_amdgcn_mfma_f32_16x16x32_bf16(a0, b0, acc, 0, 0, 0);
    acc = __builtin_amdgcn_mfma_f32_16x16x32_bf16(a1, b1, acc, 0, 0, 0);
    int col = n0 + lr;
    float bias = pb[br * 64 + col];
#pragma unroll
    for (int r = 0; r < 4; ++r) {
      int pg = grp * 64 + r0 + r;
      x1[((size_t)br * NPIX + pg) * 64 + col] =
          acc[r] + bias + x[(size_t)pg * 256 + br * 64 + col];
    }
  }
}

// ---------------- Kernel 4: GA LN1 + 2x2 mean pool ----------------
__global__ __launch_bounds__(256) void k_ga_pool(
    const float* __restrict__ x, const float* __restrict__ g,
    const float* __restrict__ bta, float* __restrict__ xa) {
  int t = blockIdx.x * 4 + (threadIdx.x >> 6);
  int lane = threadIdx.x & 63;
  int b = t / 784, rem = t % 784, hp = rem / 28, wp = rem % 28;
  float gg = g[lane], bb = bta[lane];
  float s = 0.f;
#pragma unroll
  for (int dy = 0; dy < 2; ++dy)
#pragma unroll
    for (int dx = 0; dx < 2; ++dx) {
      int pix = b * 3136 + (hp * 2 + dy) * 56 + (wp * 2 + dx);
      float v = x[(size_t)pix * 256 + 192 + lane];
      float s1 = wsum(v), s2 = wsum(v * v);
      float m = s1 * (1.f / 64.f);
      float var = s2 * (1.f / 64.f) - m * m;
      s += (v - m) * rsqrtf(var + 1e-5f) * gg + bb;
    }
  xa[(size_t)t * 64 + lane] = 0.25f * s;
}

// ---------------- Kernel 5: GA QKV GEMM -> bf16 qb/kb + transposed vT ----
// grid 99: blocks 0..97 compute 32 tokens each; block 98 zero-pads n=784..799
__global__ __launch_bounds__(256) void k_ga_qkv(
    const float* __restrict__ xa, const float* __restrict__ w,
    const float* __restrict__ bias, ushort* __restrict__ qb,
    ushort* __restrict__ kb, ushort* __restrict__ vT) {
  if (blockIdx.x == 98) {
    int t = threadIdx.x;
    for (int i = t; i < 4096; i += 256) {
      int bh = i >> 8, rem = i & 255;
      int n = 784 + (rem >> 4), d = rem & 15;
      qb[((size_t)bh * 800 + n) * 16 + d] = 0;
      kb[((size_t)bh * 800 + n) * 16 + d] = 0;
      vT[((size_t)bh * 16 + d) * 800 + n] = 0;
    }
    return;
  }
  __shared__ float sW[64 * 192];
  __shared__ float sB[192];
  __shared__ float sX[32][65];
  int grp = blockIdx.x;
  int tid = threadIdx.x;
  for (int i = tid * 4; i < 64 * 192; i += 1024)
    *(float4*)&sW[i] = *(const float4*)&w[i];
  if (tid < 192) sB[tid] = bias[tid];
  for (int i = tid * 4; i < 32 * 64; i += 1024) {
    int p = i >> 6, c = i & 63;
    float4 v = *(const float4*)&xa[(size_t)(grp * 32 + p) * 64 + c];
    sX[p][c] = v.x; sX[p][c + 1] = v.y; sX[p][c + 2] = v.z; sX[p][c + 3] = v.w;
  }
  __syncthreads();
  int pl = tid >> 3, o0 = (tid & 7) * 24;
  float acc[24];
#pragma unroll
  for (int j = 0; j < 24; ++j) acc[j] = sB[o0 + j];
  for (int c = 0; c < 64; ++c) {
    float a = sX[pl][c];
    const float4* wr = (const float4*)&sW[c * 192 + o0];
#pragma unroll
    for (int j4 = 0; j4 < 6; ++j4) {
      float4 w4 = wr[j4];
      acc[4 * j4 + 0] = fmaf(a, w4.x, acc[4 * j4 + 0]);
      acc[4 * j4 + 1] = fmaf(a, w4.y, acc[4 * j4 + 1]);
      acc[4 * j4 + 2] = fmaf(a, w4.z, acc[4 * j4 + 2]);
      acc[4 * j4 + 3] = fmaf(a, w4.w, acc[4 * j4 + 3]);
    }
  }
  int token = grp * 32 + pl;
  int b = token / 784, nn = token % 784;
#pragma unroll
  for (int j = 0; j < 24; ++j) {
    int col = o0 + j;
    float v = acc[j];
    if (col < 64) {
      int h = col >> 4, d = col & 15;
      qb[((size_t)(b * 4 + h) * 800 + nn) * 16 + d] = f2bf(v * 0.25f);
    } else if (col < 128) {
      int c = col - 64, h = c >> 4, d = c & 15;
      kb[((size_t)(b * 4 + h) * 800 + nn) * 16 + d] = f2bf(v);
    } else {
      int c = col - 128, h = c >> 4, d = c & 15;
      vT[((size_t)(b * 4 + h) * 16 + d) * 800 + nn] = f2bf(v);
    }
  }
}

// ---------------- Kernel 6: GA attention via MFMA 32x32x16 ----------------
// 1 wave per (bh, q-tile of 32 rows); grid = 16*25 = 400 blocks x 64 thr
__global__ __launch_bounds__(64) void k_ga_attn(
    const ushort* __restrict__ qb, const ushort* __restrict__ kb,
    const ushort* __restrict__ vT, const float* __restrict__ x,
    float* __restrict__ x1g) {
  int wt = blockIdx.x;
  int bh = wt / 25, qt = wt % 25;
  int h = bh & 3, b = bh >> 2;
  int lane = threadIdx.x;
  int qrow = lane & 31, hi = lane >> 5;
  int dmod = lane & 15;
  const ushort* qbase = qb + (size_t)bh * 800 * 16;
  const ushort* kbase = kb + (size_t)bh * 800 * 16;
  const ushort* vbase = vT + (size_t)bh * 16 * 800 + (size_t)dmod * 800;
  // Q fragment (B operand): col=qrow, k=hi*8+i -> Q[qt*32+qrow][hi*8..+7]
  bf16x8 qf = *(const bf16x8*)&qbase[(qt * 32 + qrow) * 16 + hi * 8];
  float m = -1e30f, l = 0.f;
  f32x16 acc_o;
#pragma unroll
  for (int r = 0; r < 16; ++r) acc_o[r] = 0.f;
  // prefetch tile 0
  bf16x8 kf = *(const bf16x8*)&kbase[(0 + qrow) * 16 + hi * 8];
  bf16x8 vf0 = *(const bf16x8*)&vbase[0 + hi * 8];
  bf16x8 vf1 = *(const bf16x8*)&vbase[16 + hi * 8];
  for (int kt = 0; kt < 25; ++kt) {
    int nb = (kt < 24 ? kt + 1 : 24) * 32;
    bf16x8 nkf = *(const bf16x8*)&kbase[(nb + qrow) * 16 + hi * 8];
    bf16x8 nvf0 = *(const bf16x8*)&vbase[nb + hi * 8];
    bf16x8 nvf1 = *(const bf16x8*)&vbase[nb + 16 + hi * 8];
    f32x16 zero;
#pragma unroll
    for (int r = 0; r < 16; ++r) zero[r] = 0.f;
    // S^T = K * Q^T : st[r] = S[qrow][kt*32 + (r&3)+4*hi+8*(r>>2)]
    f32x16 st = __builtin_amdgcn_mfma_f32_32x32x16_bf16(kf, qf, zero, 0, 0, 0);
    float s[16];
#pragma unroll
    for (int r = 0; r < 16; ++r) s[r] = st[r];
    if (kt == 24) {  // keys 784..799 invalid (local key >= 16 <=> r >= 8)
#pragma unroll
      for (int r = 8; r < 16; ++r) s[r] = -1e30f;
    }
    float tm = s[0];
#pragma unroll
    for (int r = 1; r < 16; ++r) tm = fmaxf(tm, s[r]);
    tm = fmaxf(tm, __shfl_xor(tm, 32, 64));
    if (__any(tm > m + 8.f)) {
      float mn = fmaxf(m, tm);
      float sc = __expf(m - mn);
      l *= sc;
      m = mn;
#pragma unroll
      for (int r = 0; r < 16; ++r) {
        int row = (r & 3) + 4 * hi + 8 * (r >> 2);
        float scr = __shfl(sc, row, 64);
        acc_o[r] *= scr;
      }
    }
    uint32_t pk[8];
    float ps = 0.f;
#pragma unroll
    for (int i = 0; i < 8; ++i) {
      float p0 = __expf(s[2 * i] - m), p1 = __expf(s[2 * i + 1] - m);
      ps += p0 + p1;
      pk[i] = packbf(p0, p1);
    }
    l += ps;
#pragma unroll
    for (int t = 0; t < 2; ++t) {
      uint32_t c0 = pk[4 * t + 0], c1 = pk[4 * t + 1];
      uint32_t c2 = pk[4 * t + 2], c3 = pk[4 * t + 3];
      uint32_t b00 = __shfl((int)c0, qrow, 64), b02 = __shfl((int)c2, qrow, 64);
      uint32_t b10 = __shfl((int)c1, qrow, 64), b12 = __shfl((int)c3, qrow, 64);
      uint32_t b20 = __shfl((int)c0, qrow + 32, 64), b22 = __shfl((int)c2, qrow + 32, 64);
      uint32_t b30 = __shfl((int)c1, qrow + 32, 64), b32 = __shfl((int)c3, qrow + 32, 64);
      union { uint32_t u[4]; bf16x8 v; } pa;
      pa.u[0] = hi ? b02 : b00;
      pa.u[1] = hi ? b12 : b10;
      pa.u[2] = hi ? b22 : b20;
      pa.u[3] = hi ? b32 : b30;
      acc_o = __builtin_amdgcn_mfma_f32_32x32x16_bf16(pa.v, (t ? vf1 : vf0),
                                                      acc_o, 0, 0, 0);
    }
    kf = nkf; vf0 = nvf0; vf1 = nvf1;
  }
  l += __shfl_xor(l, 32, 64);
  float inv = 1.f / l;
  // D cols 0..15 and 16..31 duplicate (V fragment uses col&15): only lanes
  // with (lane&31)<16 write. BOTH hi halves must write (rows split by hi).
#pragma unroll
  for (int r = 0; r < 16; ++r) {
    int row = (r & 3) + 4 * hi + 8 * (r >> 2);
    float invr = __shfl(inv, row, 64);
    int n = qt * 32 + row;
    if (n < 784 && qrow < 16) {
      float o = acc_o[r] * invr;
      int hp = n / 28, wp = n % 28;
      int ch = h * 16 + dmod;
#pragma unroll
      for (int dy = 0; dy < 2; ++dy)
#pragma unroll
        for (int dx = 0; dx < 2; ++dx) {
          int pix = b * 3136 + (hp * 2 + dy) * 56 + (wp * 2 + dx);
          x1g[(size_t)pix * 64 + ch] = x[(size_t)pix * 256 + 192 + ch] + o;
        }
    }
  }
}

// ---------------- Kernel 7: LN2 + MLP + residual via MFMA ----------------
template <bool NAT>
__global__ __launch_bounds__(256) void k_mlp(
    const float* __restrict__ x1, const float* __restrict__ nat_ln2_g,
    const float* __restrict__ nat_ln2_b, const ushort* __restrict__ wT,
    const float* __restrict__ nat_f1b, const float* __restrict__ nat_f2b,
    const float* __restrict__ ga_ln2_g, const float* __restrict__ ga_ln2_b,
    const float* __restrict__ ga_f1b, const float* __restrict__ ga_f2b,
    float* __restrict__ out) {
  constexpr int H1 = NAT ? 256 : 192;
  constexpr int K2P = NAT ? 264 : 200;
  constexpr int KB = H1 / 32;
  constexpr int SW = NAT ? 256 * 72 : 192 * 72;
  __shared__ __align__(16) ushort sX[32 * 72];
  __shared__ __align__(16) ushort sH[32 * K2P];
  __shared__ __align__(16) ushort sW[SW];
  int br = NAT ? (int)(blockIdx.x / 392) : 3;
  int grp = blockIdx.x % 392;
  int tid = threadIdx.x, lane = tid & 63, wid = tid >> 6;
  const ushort* W1 = NAT ? wT + 55296 + br * 18432 : wT + 175104;
  const ushort* W2 = NAT ? wT + 110592 + br * 16896 : wT + 188928;
  const float* B1 = NAT ? nat_f1b + br * 256 : ga_f1b;
  const float* B2 = NAT ? nat_f2b + br * 64 : ga_f2b;
  const float* G = NAT ? nat_ln2_g + br * 64 : ga_ln2_g;
  const float* Bt = NAT ? nat_ln2_b + br * 64 : ga_ln2_b;
  const float* xin = x1 + ((size_t)br * NPIX + grp * 32) * 64;
  constexpr int NW1 = H1 * 9;
  for (int i = tid; i < NW1; i += 256) ((uint4*)sW)[i] = ((const uint4*)W1)[i];
  float g = G[lane], bb = Bt[lane];
#pragma unroll
  for (int i = 0; i < 8; ++i) {
    int pl = wid * 8 + i;
    float v = xin[pl * 64 + lane];
    float s1 = wsum(v), s2 = wsum(v * v);
    float m = s1 * (1.f / 64.f);
    float var = s2 * (1.f / 64.f) - m * m;
    sX[pl * 72 + lane] = f2bf((v - m) * rsqrtf(var + 1e-5f) * g + bb);
  }
  __syncthreads();
  int lr = lane & 15, lk = (lane >> 4) * 8;
  int m0 = (wid & 1) * 16;
  int r0 = (lane >> 4) * 4;
  bf16x8 a0 = *(const bf16x8*)&sX[(m0 + lr) * 72 + lk];
  bf16x8 a1 = *(const bf16x8*)&sX[(m0 + lr) * 72 + 32 + lk];
#pragma unroll
  for (int t2 = 0; t2 < H1 / 32; ++t2) {
    int n0 = ((wid >> 1) + 2 * t2) * 16;
    bf16x8 b0 = *(const bf16x8*)&sW[(n0 + lr) * 72 + lk];
    bf16x8 b1 = *(const bf16x8*)&sW[(n0 + lr) * 72 + 32 + lk];
    f32x4 acc = {0.f, 0.f, 0.f, 0.f};
    acc = __builtin_amdgcn_mfma_f32_16x16x32_bf16(a0, b0, acc, 0, 0, 0);
    acc = __builtin_amdgcn_mfma_f32_16x16x32_bf16(a1, b1, acc, 0, 0, 0);
    int col = n0 + lr;
    float b1v = B1[col];
#pragma unroll
    for (int r = 0; r < 4; ++r)
      sH[(m0 + r0 + r) * K2P + col] = f2bf(gelu_fast(acc[r] + b1v));
  }
  __syncthreads();
  constexpr int NW2 = 64 * K2P / 8;
  for (int i = tid; i < NW2; i += 256) ((uint4*)sW)[i] = ((const uint4*)W2)[i];
  __syncthreads();
  bf16x8 af[KB];
#pragma unroll
  for (int kb = 0; kb < KB; ++kb)
    af[kb] = *(const bf16x8*)&sH[(m0 + lr) * K2P + kb * 32 + lk];
#pragma unroll
  for (int u = 0; u < 2; ++u) {
    int n0 = ((wid >> 1) + 2 * u) * 16;
    f32x4 acc = {0.f, 0.f, 0.f, 0.f};
#pragma unroll
    for (int kb = 0; kb < KB; ++kb) {
      bf16x8 bf = *(const bf16x8*)&sW[(n0 + lr) * K2P + kb * 32 + lk];
      acc = __builtin_amdgcn_mfma_f32_16x16x32_bf16(af[kb], bf, acc, 0, 0, 0);
    }
    int col = n0 + lr;
    float b2v = B2[col];
#pragma unroll
    for (int r = 0; r < 4; ++r) {
      int p = m0 + r0 + r;
      int pix = grp * 32 + p;
      out[(size_t)pix * 256 + br * 64 + col] = xin[p * 64 + col] + acc[r] + b2v;
    }
  }
}

}  // namespace

extern "C" void kernel_launch(void* const* d_in, const int* in_sizes, int n_in,
                              void* d_out, int out_size, void* d_ws, size_t ws_size,
                              hipStream_t stream) {
  const float* x = (const float*)d_in[0];
  const float* nat_ln1_g = (const float*)d_in[1];
  const float* nat_ln1_b = (const float*)d_in[2];
  const float* nat_qkv_w = (const float*)d_in[3];
  const float* nat_qkv_b = (const float*)d_in[4];
  const float* nat_rpb = (const float*)d_in[5];
  const float* nat_proj_w = (const float*)d_in[6];
  const float* nat_proj_b = (const float*)d_in[7];
  const float* nat_ln2_g = (const float*)d_in[8];
  const float* nat_ln2_b = (const float*)d_in[9];
  const float* nat_fc1_w = (const float*)d_in[10];
  const float* nat_fc1_b = (const float*)d_in[11];
  const float* nat_fc2_w = (const float*)d_in[12];
  const float* nat_fc2_b = (const float*)d_in[13];
  const float* ga_ln1_g = (const float*)d_in[14];
  const float* ga_ln1_b = (const float*)d_in[15];
  const float* ga_qkv_w = (const float*)d_in[16];
  const float* ga_qkv_b = (const float*)d_in[17];
  const float* ga_ln2_g = (const float*)d_in[18];
  const float* ga_ln2_b = (const float*)d_in[19];
  const float* ga_fc1_w = (const float*)d_in[20];
  const float* ga_fc1_b = (const float*)d_in[21];
  const float* ga_fc2_w = (const float*)d_in[22];
  const float* ga_fc2_b = (const float*)d_in[23];

  uint8_t* w8 = (uint8_t*)d_ws;
  float*  qn     = (float*)w8;                        //  9,633,792 B
  ushort* kvn    = (ushort*)(w8 + 9633792);           //  9,633,792 B
  ushort* att    = (ushort*)(w8 + 19267584);          //  4,816,896 B
  float*  x1     = (float*)(w8 + 24084480);           // 12,845,056 B
  float*  xa     = (float*)(w8 + 36929536);           //    802,816 B
  ushort* wT     = (ushort*)(w8 + 37732352);          //    403,456 B
  ushort* qgb    = (ushort*)(w8 + 38135808);          //    409,600 B
  ushort* kgb    = (ushort*)(w8 + 38545408);          //    409,600 B
  ushort* vgT    = (ushort*)(w8 + 38955008);          //    409,600 B
  // total ~39.4 MB

  k_prep<<<dim3(789), dim3(256), 0, stream>>>(nat_qkv_w, nat_proj_w, nat_fc1_w,
                                              nat_fc2_w, ga_qkv_w, ga_fc1_w,
                                              ga_fc2_w, wT);
  k_nat_ln_qkv<<<dim3(588), dim3(256), 0, stream>>>(x, nat_ln1_g, nat_ln1_b, wT,
                                                    nat_qkv_b, qn, kvn);
  k_ga_pool<<<dim3(784), dim3(256), 0, stream>>>(x, ga_ln1_g, ga_ln1_b, xa);
  k_ga_qkv<<<dim3(99), dim3(256), 0, stream>>>(xa, ga_qkv_w, ga_qkv_b, qgb, kgb, vgT);
  k_nat_attn<<<dim3(588), dim3(256), 0, stream>>>(qn, kvn, nat_rpb, att);
  k_nat_proj<<<dim3(588), dim3(256), 0, stream>>>(att, wT, nat_proj_b, x, x1);
  k_ga_attn<<<dim3(400), dim3(64), 0, stream>>>(qgb, kgb, vgT, x,
                                                x1 + (size_t)3 * NPIX * 64);
  k_mlp<true><<<dim3(1176), dim3(256), 0, stream>>>(
      x1, nat_ln2_g, nat_ln2_b, wT, nat_fc1_b, nat_fc2_b, ga_ln2_g, ga_ln2_b,
      ga_fc1_b, ga_fc2_b, (float*)d_out);
  k_mlp<false><<<dim3(392), dim3(256), 0, stream>>>(
      x1, nat_ln2_g, nat_ln2_b, wT, nat_fc1_b, nat_fc2_b, ga_ln2_g, ga_ln2_b,
      ga_fc1_b, ga_fc2_b, (float*)d_out);
}